// Round 7
// baseline (2144.241 us; speedup 1.0000x reference)
//
#include <hip/hip_runtime.h>
#include <math.h>

#define N_NODES 50000
#define F_IN    512
#define HDIM    256
#define L_OUT   52
#define E_EDGES 1600000

typedef short short8 __attribute__((ext_vector_type(8)));
typedef unsigned short u16x8 __attribute__((ext_vector_type(8)));
typedef float f32x4 __attribute__((ext_vector_type(4)));
typedef float f32x2 __attribute__((ext_vector_type(2)));

__device__ __forceinline__ float bf2f(unsigned short u) {
    unsigned int x = ((unsigned int)u) << 16;
    return __builtin_bit_cast(float, x);
}
__device__ __forceinline__ unsigned short f2bf(float f) {
    unsigned int u = __builtin_bit_cast(unsigned int, f);
    return (unsigned short)((u + 0x7fffu + ((u >> 16) & 1u)) >> 16);
}
__device__ __forceinline__ unsigned char f2fp8(float f) {
    int pk = __builtin_amdgcn_cvt_pk_fp8_f32(f, 0.f, 0, false);
    return (unsigned char)(pk & 0xff);
}
__device__ __forceinline__ void fp8x4_to_f32(unsigned int u, float* f) {
    f32x2 p0 = __builtin_amdgcn_cvt_pk_f32_fp8((int)u, false);
    f32x2 p1 = __builtin_amdgcn_cvt_pk_f32_fp8((int)u, true);
    f[0] = p0[0]; f[1] = p0[1]; f[2] = p1[0]; f[3] = p1[1];
}
__device__ __forceinline__ void gload16(const unsigned short* g, unsigned short* l) {
    __builtin_amdgcn_global_load_lds(
        (const __attribute__((address_space(1))) unsigned int*)(g),
        (__attribute__((address_space(3))) unsigned int*)(l), 16, 0, 0);
}

// ------------------------------------------- CSR build (both branches fused)

__global__ void k_count2(const int* __restrict__ d1, const int* __restrict__ d2,
                         int* __restrict__ c1, int* __restrict__ c2, int E) {
    int i = blockIdx.x * blockDim.x + threadIdx.x;
    int stride = gridDim.x * blockDim.x;
    int tot = 2 * E;
    for (; i < tot; i += stride) {
        if (i < E) atomicAdd(&c1[d1[i]], 1);
        else       atomicAdd(&c2[d2[i - E]], 1);
    }
}

__global__ void k_dinv2(const int* __restrict__ c1, const int* __restrict__ c2,
                        float* __restrict__ v1, float* __restrict__ v2, int n) {
    int i = blockIdx.x * blockDim.x + threadIdx.x;
    if (i < n) v1[i] = rsqrtf((float)(c1[i] + 1));
    else if (i < 2 * n) v2[i - n] = rsqrtf((float)(c2[i - n] + 1));
}

__global__ void k_scan1f(const int* __restrict__ c1, const int* __restrict__ c2,
                         int* __restrict__ i1, int* __restrict__ i2,
                         int* __restrict__ b1, int* __restrict__ b2, int n) {
    const int* cnt = blockIdx.y ? c2 : c1;
    int* incl = blockIdx.y ? i2 : i1;
    int* bsum = blockIdx.y ? b2 : b1;
    __shared__ int s[256];
    int tid = threadIdx.x;
    int idx = blockIdx.x * 256 + tid;
    int v = (idx < n) ? cnt[idx] : 0;
    s[tid] = v;
    __syncthreads();
#pragma unroll
    for (int off = 1; off < 256; off <<= 1) {
        int t = (tid >= off) ? s[tid - off] : 0;
        __syncthreads();
        s[tid] += t;
        __syncthreads();
    }
    if (idx < n) incl[idx] = s[tid];
    if (tid == 255) bsum[blockIdx.x] = s[255];
}

__global__ void k_scan2f(int* __restrict__ b1, int* __restrict__ b2,
                         int* __restrict__ r1, int* __restrict__ r2, int nb, int n) {
    int* bsum = blockIdx.x ? b2 : b1;
    int* rowptr = blockIdx.x ? r2 : r1;
    __shared__ int s[256];
    int tid = threadIdx.x;
    int v = (tid < nb) ? bsum[tid] : 0;
    s[tid] = v;
    __syncthreads();
#pragma unroll
    for (int off = 1; off < 256; off <<= 1) {
        int t = (tid >= off) ? s[tid - off] : 0;
        __syncthreads();
        s[tid] += t;
        __syncthreads();
    }
    if (tid < nb) bsum[tid] = s[tid] - v;
    if (tid == nb - 1) rowptr[n] = s[tid];
}

__global__ void k_scan3f(const int* __restrict__ i1, const int* __restrict__ i2,
                         const int* __restrict__ c1, const int* __restrict__ c2,
                         const int* __restrict__ b1, const int* __restrict__ b2,
                         int* __restrict__ r1, int* __restrict__ r2, int n) {
    const int* incl = blockIdx.y ? i2 : i1;
    const int* cnt  = blockIdx.y ? c2 : c1;
    const int* bsum = blockIdx.y ? b2 : b1;
    int* rowptr     = blockIdx.y ? r2 : r1;
    int i = blockIdx.x * blockDim.x + threadIdx.x;
    if (i < n) rowptr[i] = incl[i] - cnt[i] + bsum[i >> 8];
}

__global__ void k_fill2(const int* __restrict__ s1, const int* __restrict__ d1,
                        const int* __restrict__ s2, const int* __restrict__ d2,
                        const int* __restrict__ rp1, const int* __restrict__ rp2,
                        int* __restrict__ cu1, int* __restrict__ cu2,
                        const float* __restrict__ v1, const float* __restrict__ v2,
                        int2* __restrict__ cw1, int2* __restrict__ cw2, int E) {
    int i = blockIdx.x * blockDim.x + threadIdx.x;
    int stride = gridDim.x * blockDim.x;
    int tot = 2 * E;
    for (; i < tot; i += stride) {
        int br = i >= E;
        int e = br ? i - E : i;
        const int* S = br ? s2 : s1;
        const int* D = br ? d2 : d1;
        const int* RP = br ? rp2 : rp1;
        int* CU = br ? cu2 : cu1;
        const float* V = br ? v2 : v1;
        int2* CW = br ? cw2 : cw1;
        int s = S[e], d = D[e];
        int p = atomicAdd(&CU[d], 1);
        float w = V[s] * V[d];
        CW[RP[d] + p] = make_int2(s, __builtin_bit_cast(int, w));
    }
}

// ------------------------------------------------------------- conversions

__global__ void k_f2b2(const float* __restrict__ x1, const float* __restrict__ x2,
                       unsigned short* __restrict__ o1, unsigned short* __restrict__ o2,
                       int n4) {
    int i = blockIdx.x * blockDim.x + threadIdx.x;
    int stride = gridDim.x * blockDim.x;
    int tot = 2 * n4;
    for (; i < tot; i += stride) {
        int br = i >= n4;
        int e = br ? i - n4 : i;
        float4 v = ((const float4*)(br ? x2 : x1))[e];
        ushort4 o;
        o.x = f2bf(v.x); o.y = f2bf(v.y); o.z = f2bf(v.z); o.w = f2bf(v.w);
        ((ushort4*)(br ? o2 : o1))[e] = o;
    }
}

// fused weight transpose: fp32 [K][N] -> bf16 [Npad][K], zero-padded rows
struct WDesc { const float* in; unsigned short* out; int K; int N; int Npad; };
struct WPack { WDesc d[10]; };

__global__ void k_wconv(WPack p) {
    WDesc w = p.d[blockIdx.y];
    int total = w.K * w.Npad;
    int idx = blockIdx.x * 256 + threadIdx.x;
    if (idx >= total) return;
    int n = idx / w.K, k = idx - n * w.K;
    w.out[idx] = (n < w.N) ? f2bf(w.in[(size_t)k * w.N + n]) : (unsigned short)0;
}

// ------- aggregation: wave/node, 4 neighbor-streams x 8-deep, 16B fp8 loads
//         (32 rows = 8KB in flight per wave)

__global__ void k_agg(const unsigned char* __restrict__ g, const int* __restrict__ rowptr,
                      const int2* __restrict__ cw,
                      const float* __restrict__ dinv,
                      const float* __restrict__ bias, unsigned short* __restrict__ out,
                      int n, int do_relu) {
    int gtid = blockIdx.x * blockDim.x + threadIdx.x;
    int wid = gtid >> 6;
    if (wid >= n) return;
    int lane = threadIdx.x & 63;
    int q = lane >> 4;      // neighbor stream 0..3
    int fl = lane & 15;     // 16B slice of the 256B fp8 row

    float a[16];
#pragma unroll
    for (int k = 0; k < 16; k++) a[k] = 0.f;

    int r0 = rowptr[wid], r1 = rowptr[wid + 1];

    int base = r0;
    for (; base + 32 <= r1; base += 32) {
        int2 c[8]; uint4 v[8];
#pragma unroll
        for (int t = 0; t < 8; t++) c[t] = cw[base + 4 * t + q];
#pragma unroll
        for (int t = 0; t < 8; t++)
            v[t] = ((const uint4*)(g + (size_t)c[t].x * HDIM))[fl];
#pragma unroll
        for (int t = 0; t < 8; t++) {
            float w = __builtin_bit_cast(float, c[t].y);
            float f[16];
            fp8x4_to_f32(v[t].x, f);
            fp8x4_to_f32(v[t].y, f + 4);
            fp8x4_to_f32(v[t].z, f + 8);
            fp8x4_to_f32(v[t].w, f + 12);
#pragma unroll
            for (int k = 0; k < 16; k++) a[k] = fmaf(f[k], w, a[k]);
        }
    }
    if (base < r1) {  // remainder 1..31 neighbors, zero-weight padding
        int2 c[8]; uint4 v[8]; float w[8];
#pragma unroll
        for (int t = 0; t < 8; t++) {
            int idx = base + 4 * t + q;
            int ok = idx < r1;
            c[t] = cw[ok ? idx : r0];
            w[t] = ok ? __builtin_bit_cast(float, c[t].y) : 0.f;
        }
#pragma unroll
        for (int t = 0; t < 8; t++)
            v[t] = ((const uint4*)(g + (size_t)c[t].x * HDIM))[fl];
#pragma unroll
        for (int t = 0; t < 8; t++) {
            float f[16];
            fp8x4_to_f32(v[t].x, f);
            fp8x4_to_f32(v[t].y, f + 4);
            fp8x4_to_f32(v[t].z, f + 8);
            fp8x4_to_f32(v[t].w, f + 12);
#pragma unroll
            for (int k = 0; k < 16; k++) a[k] = fmaf(f[k], w[t], a[k]);
        }
    }

    // combine the 4 streams
#pragma unroll
    for (int k = 0; k < 16; k++) {
        a[k] += __shfl_xor(a[k], 16);
        a[k] += __shfl_xor(a[k], 32);
    }

    // self-loop + bias + activation (redundant across streams, store once)
    float di = dinv[wid];
    float w0 = di * di;
    uint4 sv = ((const uint4*)(g + (size_t)wid * HDIM))[fl];
    float sf[16];
    fp8x4_to_f32(sv.x, sf); fp8x4_to_f32(sv.y, sf + 4);
    fp8x4_to_f32(sv.z, sf + 8); fp8x4_to_f32(sv.w, sf + 12);
    const float4* b4 = (const float4*)(bias + fl * 16);
    float4 bb[4] = {b4[0], b4[1], b4[2], b4[3]};
    float bf_[16] = {bb[0].x, bb[0].y, bb[0].z, bb[0].w,
                     bb[1].x, bb[1].y, bb[1].z, bb[1].w,
                     bb[2].x, bb[2].y, bb[2].z, bb[2].w,
                     bb[3].x, bb[3].y, bb[3].z, bb[3].w};
    u16x8 o0, o1;
#pragma unroll
    for (int k = 0; k < 16; k++) {
        float x = fmaf(sf[k], w0, a[k]) + bf_[k];
        if (do_relu) x = fmaxf(x, 0.f);
        if (k < 8) o0[k] = f2bf(x); else o1[k - 8] = f2bf(x);
    }
    if (q == 0) {
        u16x8* dst = (u16x8*)(out + (size_t)wid * HDIM + fl * 16);
        dst[0] = o0; dst[1] = o1;
    }
}

// --------------------------------------------------- bf16 MFMA GEMM 128x128
// EPI 0: raw -> fp8 C.  EPI 1: bias+relu -> bf16.  EPI 2: bias+sigmoid -> fp32.

template <int EPI>
__device__ __forceinline__ void gemm_body(const unsigned short* __restrict__ A,
                                          const unsigned short* __restrict__ Bt,
                                          const float* __restrict__ bias,
                                          void* __restrict__ Cout,
                                          int M, int K, int Nc,
                                          unsigned short* As, unsigned short* Bs,
                                          int mb, int nb) {
    int tid = threadIdx.x;
    int wid = tid >> 6, lane = tid & 63;
    int wr = wid >> 1, wc = wid & 1;

    int sr = tid >> 2;
    int ssl = (tid & 3) ^ ((sr >> 1) & 3);
    int ar0 = mb + sr;      if (ar0 > M - 1) ar0 = M - 1;
    int ar1 = mb + sr + 64; if (ar1 > M - 1) ar1 = M - 1;
    const unsigned short* gA0 = A + (size_t)ar0 * K + ssl * 8;
    const unsigned short* gA1 = A + (size_t)ar1 * K + ssl * 8;
    const unsigned short* gB0 = Bt + (size_t)(nb + sr) * K + ssl * 8;
    const unsigned short* gB1 = Bt + (size_t)(nb + sr + 64) * K + ssl * 8;
    unsigned short* ldsA = As + tid * 8;
    unsigned short* ldsB = Bs + tid * 8;

    f32x4 acc[4][4];
#pragma unroll
    for (int m = 0; m < 4; m++)
#pragma unroll
        for (int n = 0; n < 4; n++) acc[m][n] = (f32x4){0.f, 0.f, 0.f, 0.f};

    int l15 = lane & 15, ks = lane >> 4;

    for (int k0 = 0; k0 < K; k0 += 32) {
        gload16(gA0 + k0, ldsA);
        gload16(gA1 + k0, ldsA + 2048);
        gload16(gB0 + k0, ldsB);
        gload16(gB1 + k0, ldsB + 2048);
        __syncthreads();

        short8 af[4], bfr[4];
#pragma unroll
        for (int m = 0; m < 4; m++) {
            int row = wr * 64 + m * 16 + l15;
            int slot = ks ^ ((row >> 1) & 3);
            af[m] = *(const short8*)((const char*)As + row * 64 + slot * 16);
        }
#pragma unroll
        for (int n = 0; n < 4; n++) {
            int row = wc * 64 + n * 16 + l15;
            int slot = ks ^ ((row >> 1) & 3);
            bfr[n] = *(const short8*)((const char*)Bs + row * 64 + slot * 16);
        }
#pragma unroll
        for (int m = 0; m < 4; m++)
#pragma unroll
            for (int n = 0; n < 4; n++)
                acc[m][n] = __builtin_amdgcn_mfma_f32_16x16x32_bf16(af[m], bfr[n], acc[m][n], 0, 0, 0);
        __syncthreads();
    }

    int lq = lane >> 4;
#pragma unroll
    for (int m = 0; m < 4; m++) {
#pragma unroll
        for (int n = 0; n < 4; n++) {
            int gcol = nb + wc * 64 + n * 16 + l15;
#pragma unroll
            for (int r = 0; r < 4; r++) {
                int grow = mb + wr * 64 + m * 16 + lq * 4 + r;
                if (grow >= M) continue;
                float v = acc[m][n][r];
                if (EPI == 0) {
                    ((unsigned char*)Cout)[(size_t)grow * Nc + gcol] = f2fp8(v);
                } else if (EPI == 1) {
                    v += bias[gcol];
                    v = fmaxf(v, 0.f);
                    ((unsigned short*)Cout)[(size_t)grow * Nc + gcol] = f2bf(v);
                } else {
                    if (gcol < Nc) {
                        v += bias[gcol];
                        v = 1.f / (1.f + expf(-v));
                        ((float*)Cout)[(size_t)grow * Nc + gcol] = v;
                    }
                }
            }
        }
    }
}

template <int EPI>
__global__ __launch_bounds__(256) void k_gemm(const unsigned short* __restrict__ A,
                                              const unsigned short* __restrict__ Bt,
                                              const float* __restrict__ bias,
                                              void* __restrict__ Cout,
                                              int M, int K, int Nc) {
    __shared__ __align__(16) unsigned short As[128 * 32];
    __shared__ __align__(16) unsigned short Bs[128 * 32];
    gemm_body<EPI>(A, Bt, bias, Cout, M, K, Nc, As, Bs,
                   blockIdx.y * 128, blockIdx.x * 128);
}

// two-branch fused GEMM (blockIdx.z selects branch)
template <int EPI>
__global__ __launch_bounds__(256) void k_gemm2(const unsigned short* __restrict__ A0,
                                               const unsigned short* __restrict__ A1,
                                               const unsigned short* __restrict__ B0,
                                               const unsigned short* __restrict__ B1,
                                               const float* __restrict__ b0,
                                               const float* __restrict__ b1,
                                               void* __restrict__ C0,
                                               void* __restrict__ C1,
                                               int M, int K, int Nc) {
    __shared__ __align__(16) unsigned short As[128 * 32];
    __shared__ __align__(16) unsigned short Bs[128 * 32];
    int br = blockIdx.z;
    gemm_body<EPI>(br ? A1 : A0, br ? B1 : B0, br ? b1 : b0, br ? C1 : C0,
                   M, K, Nc, As, Bs, blockIdx.y * 128, blockIdx.x * 128);
}

// ------------------------------------------------------------- gate fusion

__global__ void k_gate(const unsigned short* __restrict__ h1, const unsigned short* __restrict__ h2,
                       const float* __restrict__ w1, const float* __restrict__ w1b,
                       const float* __restrict__ w2, const float* __restrict__ w2b,
                       unsigned short* __restrict__ m, int n) {
    int gtid = blockIdx.x * blockDim.x + threadIdx.x;
    int wid = gtid >> 6;
    int lane = threadIdx.x & 63;
    if (wid >= n) return;
    ushort4 av = ((const ushort4*)(h1 + (size_t)wid * HDIM))[lane];
    ushort4 bv = ((const ushort4*)(h2 + (size_t)wid * HDIM))[lane];
    float4 wa = ((const float4*)w1)[lane];
    float4 wb = ((const float4*)w2)[lane];
    float a0 = bf2f(av.x), a1 = bf2f(av.y), a2 = bf2f(av.z), a3 = bf2f(av.w);
    float b0 = bf2f(bv.x), b1 = bf2f(bv.y), b2 = bf2f(bv.z), b3 = bf2f(bv.w);
    float d1 = a0 * wa.x + a1 * wa.y + a2 * wa.z + a3 * wa.w;
    float d2 = b0 * wb.x + b1 * wb.y + b2 * wb.z + b3 * wb.w;
    for (int off = 32; off > 0; off >>= 1) {
        d1 += __shfl_xor(d1, off);
        d2 += __shfl_xor(d2, off);
    }
    float f1 = 1.f / (1.f + expf(-(d1 + w1b[0])));
    float f2 = 1.f / (1.f + expf(-(d2 + w2b[0])));
    float f = f1 / (f1 + f2);
    ushort4 o;
    o.x = f2bf(f * a0 + (1.f - f) * b0);
    o.y = f2bf(f * a1 + (1.f - f) * b1);
    o.z = f2bf(f * a2 + (1.f - f) * b2);
    o.w = f2bf(f * a3 + (1.f - f) * b3);
    ((ushort4*)(m + (size_t)wid * HDIM))[lane] = o;
}

// ------------------------------------------------------------------ launch

extern "C" void kernel_launch(void* const* d_in, const int* in_sizes, int n_in,
                              void* d_out, int out_size, void* d_ws, size_t ws_size,
                              hipStream_t stream) {
    (void)n_in; (void)out_size; (void)ws_size;
    const int N = N_NODES, E = E_EDGES;

    const float* x1; const float* x2; const int* ei1; const int* ei2;
    if (in_sizes[1] == 2 * E) {
        x1 = (const float*)d_in[0]; ei1 = (const int*)d_in[1];
        x2 = (const float*)d_in[2]; ei2 = (const int*)d_in[3];
    } else {
        x1 = (const float*)d_in[0]; x2 = (const float*)d_in[1];
        ei1 = (const int*)d_in[2]; ei2 = (const int*)d_in[3];
    }
    const float* W[2][4]; const float* Bv[2][4];
    int idx = 4;
    for (int br = 0; br < 2; br++)
        for (int l = 0; l < 4; l++) {
            W[br][l] = (const float*)d_in[idx++];
            Bv[br][l] = (const float*)d_in[idx++];
        }
    const float* w1W  = (const float*)d_in[20];
    const float* w1b  = (const float*)d_in[21];
    const float* w2W  = (const float*)d_in[22];
    const float* w2b  = (const float*)d_in[23];
    const float* finW = (const float*)d_in[24];
    const float* finb = (const float*)d_in[25];
    const float* outW = (const float*)d_in[26];
    const float* outb = (const float*)d_in[27];
    float* out = (float*)d_out;

    size_t off = 0;
    auto alloc = [&](size_t bytes) {
        void* p = (char*)d_ws + off;
        off = (off + bytes + 255) & ~(size_t)255;
        return p;
    };
    unsigned short* x1b = (unsigned short*)alloc((size_t)N * F_IN * 2);  // also fin-out t
    unsigned short* x2b = (unsigned short*)alloc((size_t)N * F_IN * 2);
    unsigned char*  g8a = (unsigned char*)alloc((size_t)N * HDIM);
    unsigned char*  g8b = (unsigned char*)alloc((size_t)N * HDIM);
    unsigned short* mb_ = (unsigned short*)alloc((size_t)N * HDIM * 2);
    unsigned short* h1b = (unsigned short*)alloc((size_t)N * HDIM * 2);
    unsigned short* h2b = (unsigned short*)alloc((size_t)N * HDIM * 2);
    unsigned short* Wt[2][4];
    Wt[0][0] = (unsigned short*)alloc((size_t)HDIM * F_IN * 2);
    for (int l = 1; l < 4; l++) Wt[0][l] = (unsigned short*)alloc((size_t)HDIM * HDIM * 2);
    Wt[1][0] = (unsigned short*)alloc((size_t)HDIM * F_IN * 2);
    for (int l = 1; l < 4; l++) Wt[1][l] = (unsigned short*)alloc((size_t)HDIM * HDIM * 2);
    unsigned short* finWt = (unsigned short*)alloc((size_t)HDIM * HDIM * 2);
    unsigned short* outWt = (unsigned short*)alloc((size_t)128 * HDIM * 2);
    int2* cw1   = (int2*)alloc((size_t)E * 8);
    int2* cw2   = (int2*)alloc((size_t)E * 8);
    int* rp1    = (int*)alloc((size_t)(N + 1) * 4);
    int* rp2    = (int*)alloc((size_t)(N + 1) * 4);
    int* incl1  = (int*)alloc((size_t)N * 4);
    int* incl2  = (int*)alloc((size_t)N * 4);
    int* bsum1  = (int*)alloc((size_t)256 * 4);
    int* bsum2  = (int*)alloc((size_t)256 * 4);
    int* cnt1   = (int*)alloc((size_t)N * 4);
    int* cnt2   = (int*)alloc((size_t)N * 4);
    int* cur1   = (int*)alloc((size_t)N * 4);
    int* cur2   = (int*)alloc((size_t)N * 4);
    float* di1  = (float*)alloc((size_t)N * 4);
    float* di2  = (float*)alloc((size_t)N * 4);

    const int BLK = 256;
    int nwaves_grid = (N * 64 + BLK - 1) / BLK;   // 12500
    int nchunks = (N + 255) / 256;                // 196
    int mtiles = (N + 127) / 128;                 // 391
    dim3 grid_h(HDIM / 128, mtiles);
    dim3 grid_h2(HDIM / 128, mtiles, 2);
    dim3 grid_o(1, mtiles);

    // fused weight conversion (10 transposes, outW zero-padded to 128 rows)
    WPack wp;
    wp.d[0] = {W[0][0], Wt[0][0], F_IN, HDIM, HDIM};
    wp.d[1] = {W[0][1], Wt[0][1], HDIM, HDIM, HDIM};
    wp.d[2] = {W[0][2], Wt[0][2], HDIM, HDIM, HDIM};
    wp.d[3] = {W[0][3], Wt[0][3], HDIM, HDIM, HDIM};
    wp.d[4] = {W[1][0], Wt[1][0], F_IN, HDIM, HDIM};
    wp.d[5] = {W[1][1], Wt[1][1], HDIM, HDIM, HDIM};
    wp.d[6] = {W[1][2], Wt[1][2], HDIM, HDIM, HDIM};
    wp.d[7] = {W[1][3], Wt[1][3], HDIM, HDIM, HDIM};
    wp.d[8] = {finW, finWt, HDIM, HDIM, HDIM};
    wp.d[9] = {outW, outWt, HDIM, L_OUT, 128};
    k_wconv<<<dim3(512, 10), BLK, 0, stream>>>(wp);

    // CSR build, both branches fused
    hipMemsetAsync(cnt1, 0, (size_t)N * 4, stream);
    hipMemsetAsync(cnt2, 0, (size_t)N * 4, stream);
    hipMemsetAsync(cur1, 0, (size_t)N * 4, stream);
    hipMemsetAsync(cur2, 0, (size_t)N * 4, stream);
    k_count2<<<2048, BLK, 0, stream>>>(ei1 + E, ei2 + E, cnt1, cnt2, E);
    k_scan1f<<<dim3(nchunks, 2), BLK, 0, stream>>>(cnt1, cnt2, incl1, incl2, bsum1, bsum2, N);
    k_scan2f<<<2, BLK, 0, stream>>>(bsum1, bsum2, rp1, rp2, nchunks, N);
    k_scan3f<<<dim3(nchunks, 2), BLK, 0, stream>>>(incl1, incl2, cnt1, cnt2, bsum1, bsum2, rp1, rp2, N);
    k_dinv2<<<(2 * N + BLK - 1) / BLK, BLK, 0, stream>>>(cnt1, cnt2, di1, di2, N);
    k_fill2<<<4096, BLK, 0, stream>>>(ei1, ei1 + E, ei2, ei2 + E, rp1, rp2,
                                      cur1, cur2, di1, di2, cw1, cw2, E);
    k_f2b2<<<4096, BLK, 0, stream>>>(x1, x2, x1b, x2b, N * F_IN / 4);

    // 4 GCN layers, branch-interleaved
    for (int l = 0; l < 4; l++) {
        const unsigned short* A0 = (l == 0) ? x1b : h1b;
        const unsigned short* A1 = (l == 0) ? x2b : h2b;
        int K = (l == 0) ? F_IN : HDIM;
        int relu = (l < 3) ? 1 : 0;
        k_gemm2<0><<<grid_h2, BLK, 0, stream>>>(A0, A1, Wt[0][l], Wt[1][l],
                                                nullptr, nullptr, g8a, g8b, N, K, HDIM);
        k_agg<<<nwaves_grid, BLK, 0, stream>>>(g8a, rp1, cw1, di1, Bv[0][l], h1b, N, relu);
        k_agg<<<nwaves_grid, BLK, 0, stream>>>(g8b, rp2, cw2, di2, Bv[1][l], h2b, N, relu);
    }

    k_gate<<<nwaves_grid, BLK, 0, stream>>>(h1b, h2b, w1W, w1b, w2W, w2b, mb_, N);
    k_gemm<1><<<grid_h, BLK, 0, stream>>>(mb_, finWt, finb, x1b, N, HDIM, HDIM);
    k_gemm<2><<<grid_o, BLK, 0, stream>>>(x1b, outWt, outb, out, N, HDIM, L_OUT);
}

// Round 8
// 1146.797 us; speedup vs baseline: 1.8698x; 1.8698x over previous
//
#include <hip/hip_runtime.h>
#include <math.h>

#define N_NODES 50000
#define F_IN    512
#define HDIM    256
#define L_OUT   52
#define E_EDGES 1600000

typedef short short8 __attribute__((ext_vector_type(8)));
typedef unsigned short u16x8 __attribute__((ext_vector_type(8)));
typedef float f32x4 __attribute__((ext_vector_type(4)));
typedef float f32x2 __attribute__((ext_vector_type(2)));

__device__ __forceinline__ float bf2f(unsigned short u) {
    unsigned int x = ((unsigned int)u) << 16;
    return __builtin_bit_cast(float, x);
}
__device__ __forceinline__ unsigned short f2bf(float f) {
    unsigned int u = __builtin_bit_cast(unsigned int, f);
    return (unsigned short)((u + 0x7fffu + ((u >> 16) & 1u)) >> 16);
}
__device__ __forceinline__ unsigned char f2fp8(float f) {
    int pk = __builtin_amdgcn_cvt_pk_fp8_f32(f, 0.f, 0, false);
    return (unsigned char)(pk & 0xff);
}
__device__ __forceinline__ void gload16(const unsigned short* g, unsigned short* l) {
    __builtin_amdgcn_global_load_lds(
        (const __attribute__((address_space(1))) unsigned int*)(g),
        (__attribute__((address_space(3))) unsigned int*)(l), 16, 0, 0);
}

// ------------------------------------------- CSR build (both branches fused)

__global__ void k_count2(const int* __restrict__ d1, const int* __restrict__ d2,
                         int* __restrict__ c1, int* __restrict__ c2, int E) {
    int i = blockIdx.x * blockDim.x + threadIdx.x;
    int stride = gridDim.x * blockDim.x;
    int tot = 2 * E;
    for (; i < tot; i += stride) {
        if (i < E) atomicAdd(&c1[d1[i]], 1);
        else       atomicAdd(&c2[d2[i - E]], 1);
    }
}

__global__ void k_dinv2(const int* __restrict__ c1, const int* __restrict__ c2,
                        float* __restrict__ v1, float* __restrict__ v2, int n) {
    int i = blockIdx.x * blockDim.x + threadIdx.x;
    if (i < n) v1[i] = rsqrtf((float)(c1[i] + 1));
    else if (i < 2 * n) v2[i - n] = rsqrtf((float)(c2[i - n] + 1));
}

__global__ void k_scan1f(const int* __restrict__ c1, const int* __restrict__ c2,
                         int* __restrict__ i1, int* __restrict__ i2,
                         int* __restrict__ b1, int* __restrict__ b2, int n) {
    const int* cnt = blockIdx.y ? c2 : c1;
    int* incl = blockIdx.y ? i2 : i1;
    int* bsum = blockIdx.y ? b2 : b1;
    __shared__ int s[256];
    int tid = threadIdx.x;
    int idx = blockIdx.x * 256 + tid;
    int v = (idx < n) ? cnt[idx] : 0;
    s[tid] = v;
    __syncthreads();
#pragma unroll
    for (int off = 1; off < 256; off <<= 1) {
        int t = (tid >= off) ? s[tid - off] : 0;
        __syncthreads();
        s[tid] += t;
        __syncthreads();
    }
    if (idx < n) incl[idx] = s[tid];
    if (tid == 255) bsum[blockIdx.x] = s[255];
}

__global__ void k_scan2f(int* __restrict__ b1, int* __restrict__ b2,
                         int* __restrict__ r1, int* __restrict__ r2, int nb, int n) {
    int* bsum = blockIdx.x ? b2 : b1;
    int* rowptr = blockIdx.x ? r2 : r1;
    __shared__ int s[256];
    int tid = threadIdx.x;
    int v = (tid < nb) ? bsum[tid] : 0;
    s[tid] = v;
    __syncthreads();
#pragma unroll
    for (int off = 1; off < 256; off <<= 1) {
        int t = (tid >= off) ? s[tid - off] : 0;
        __syncthreads();
        s[tid] += t;
        __syncthreads();
    }
    if (tid < nb) bsum[tid] = s[tid] - v;
    if (tid == nb - 1) rowptr[n] = s[tid];
}

__global__ void k_scan3f(const int* __restrict__ i1, const int* __restrict__ i2,
                         const int* __restrict__ c1, const int* __restrict__ c2,
                         const int* __restrict__ b1, const int* __restrict__ b2,
                         int* __restrict__ r1, int* __restrict__ r2, int n) {
    const int* incl = blockIdx.y ? i2 : i1;
    const int* cnt  = blockIdx.y ? c2 : c1;
    const int* bsum = blockIdx.y ? b2 : b1;
    int* rowptr     = blockIdx.y ? r2 : r1;
    int i = blockIdx.x * blockDim.x + threadIdx.x;
    if (i < n) rowptr[i] = incl[i] - cnt[i] + bsum[i >> 8];
}

__global__ void k_fill2(const int* __restrict__ s1, const int* __restrict__ d1,
                        const int* __restrict__ s2, const int* __restrict__ d2,
                        const int* __restrict__ rp1, const int* __restrict__ rp2,
                        int* __restrict__ cu1, int* __restrict__ cu2,
                        const float* __restrict__ v1, const float* __restrict__ v2,
                        int2* __restrict__ cw1, int2* __restrict__ cw2, int E) {
    int i = blockIdx.x * blockDim.x + threadIdx.x;
    int stride = gridDim.x * blockDim.x;
    int tot = 2 * E;
    for (; i < tot; i += stride) {
        int br = i >= E;
        int e = br ? i - E : i;
        const int* S = br ? s2 : s1;
        const int* D = br ? d2 : d1;
        const int* RP = br ? rp2 : rp1;
        int* CU = br ? cu2 : cu1;
        const float* V = br ? v2 : v1;
        int2* CW = br ? cw2 : cw1;
        int s = S[e], d = D[e];
        int p = atomicAdd(&CU[d], 1);
        float w = V[s] * V[d];
        CW[RP[d] + p] = make_int2(s, __builtin_bit_cast(int, w));
    }
}

// ------------------------------------------------------------- conversions

__global__ void k_f2b2(const float* __restrict__ x1, const float* __restrict__ x2,
                       unsigned short* __restrict__ o1, unsigned short* __restrict__ o2,
                       int n4) {
    int i = blockIdx.x * blockDim.x + threadIdx.x;
    int stride = gridDim.x * blockDim.x;
    int tot = 2 * n4;
    for (; i < tot; i += stride) {
        int br = i >= n4;
        int e = br ? i - n4 : i;
        float4 v = ((const float4*)(br ? x2 : x1))[e];
        ushort4 o;
        o.x = f2bf(v.x); o.y = f2bf(v.y); o.z = f2bf(v.z); o.w = f2bf(v.w);
        ((ushort4*)(br ? o2 : o1))[e] = o;
    }
}

// fused weight transpose: fp32 [K][N] -> bf16 [Npad][K], zero-padded rows
struct WDesc { const float* in; unsigned short* out; int K; int N; int Npad; };
struct WPack { WDesc d[10]; };

__global__ void k_wconv(WPack p) {
    WDesc w = p.d[blockIdx.y];
    int total = w.K * w.Npad;
    int idx = blockIdx.x * 256 + threadIdx.x;
    if (idx >= total) return;
    int n = idx / w.K, k = idx - n * w.K;
    w.out[idx] = (n < w.N) ? f2bf(w.in[(size_t)k * w.N + n]) : (unsigned short)0;
}

// ------- aggregation (ROUND-6 structure): wave/node, lane-halves process
//         even/odd neighbors, 8B fp8 loads, hw cvt fp8->f32.

__global__ void k_agg(const unsigned char* __restrict__ g, const int* __restrict__ rowptr,
                      const int2* __restrict__ cw,
                      const float* __restrict__ dinv,
                      const float* __restrict__ bias, unsigned short* __restrict__ out,
                      int n, int do_relu) {
    int gtid = blockIdx.x * blockDim.x + threadIdx.x;
    int wid = gtid >> 6;
    if (wid >= n) return;
    int lane = threadIdx.x & 63;
    int half = lane >> 5;   // even/odd neighbor stream
    int fl = lane & 31;     // feature group: 8 fp8 = 8B

    float a[8];
#pragma unroll
    for (int k = 0; k < 8; k++) a[k] = 0.f;

    int r0 = rowptr[wid], r1 = rowptr[wid + 1];

    int base = r0;
    for (; base + 16 <= r1; base += 16) {
        int2 c[8]; uint2 v[8];
#pragma unroll
        for (int t = 0; t < 8; t++) c[t] = cw[base + 2 * t + half];
#pragma unroll
        for (int t = 0; t < 8; t++)
            v[t] = ((const uint2*)(g + (size_t)c[t].x * HDIM))[fl];
#pragma unroll
        for (int t = 0; t < 8; t++) {
            float w = __builtin_bit_cast(float, c[t].y);
            f32x2 p0 = __builtin_amdgcn_cvt_pk_f32_fp8((int)v[t].x, false);
            f32x2 p1 = __builtin_amdgcn_cvt_pk_f32_fp8((int)v[t].x, true);
            f32x2 p2 = __builtin_amdgcn_cvt_pk_f32_fp8((int)v[t].y, false);
            f32x2 p3 = __builtin_amdgcn_cvt_pk_f32_fp8((int)v[t].y, true);
            a[0] = fmaf(p0[0], w, a[0]); a[1] = fmaf(p0[1], w, a[1]);
            a[2] = fmaf(p1[0], w, a[2]); a[3] = fmaf(p1[1], w, a[3]);
            a[4] = fmaf(p2[0], w, a[4]); a[5] = fmaf(p2[1], w, a[5]);
            a[6] = fmaf(p3[0], w, a[6]); a[7] = fmaf(p3[1], w, a[7]);
        }
    }
    if (base < r1) {  // remainder 1..15 neighbors, zero-weight padding
        int2 c[8]; uint2 v[8]; float w[8];
#pragma unroll
        for (int t = 0; t < 8; t++) {
            int idx = base + 2 * t + half;
            int ok = idx < r1;
            c[t] = cw[ok ? idx : r0];
            w[t] = ok ? __builtin_bit_cast(float, c[t].y) : 0.f;
        }
#pragma unroll
        for (int t = 0; t < 8; t++)
            v[t] = ((const uint2*)(g + (size_t)c[t].x * HDIM))[fl];
#pragma unroll
        for (int t = 0; t < 8; t++) {
            f32x2 p0 = __builtin_amdgcn_cvt_pk_f32_fp8((int)v[t].x, false);
            f32x2 p1 = __builtin_amdgcn_cvt_pk_f32_fp8((int)v[t].x, true);
            f32x2 p2 = __builtin_amdgcn_cvt_pk_f32_fp8((int)v[t].y, false);
            f32x2 p3 = __builtin_amdgcn_cvt_pk_f32_fp8((int)v[t].y, true);
            a[0] = fmaf(p0[0], w[t], a[0]); a[1] = fmaf(p0[1], w[t], a[1]);
            a[2] = fmaf(p1[0], w[t], a[2]); a[3] = fmaf(p1[1], w[t], a[3]);
            a[4] = fmaf(p2[0], w[t], a[4]); a[5] = fmaf(p2[1], w[t], a[5]);
            a[6] = fmaf(p3[0], w[t], a[6]); a[7] = fmaf(p3[1], w[t], a[7]);
        }
    }

    // combine even/odd partial sums
#pragma unroll
    for (int k = 0; k < 8; k++) a[k] += __shfl_xor(a[k], 32);

    // self-loop + bias + activation (redundant on both halves, store once)
    float di = dinv[wid];
    float w0 = di * di;
    uint2 sv = ((const uint2*)(g + (size_t)wid * HDIM))[fl];
    f32x2 s0 = __builtin_amdgcn_cvt_pk_f32_fp8((int)sv.x, false);
    f32x2 s1 = __builtin_amdgcn_cvt_pk_f32_fp8((int)sv.x, true);
    f32x2 s2 = __builtin_amdgcn_cvt_pk_f32_fp8((int)sv.y, false);
    f32x2 s3 = __builtin_amdgcn_cvt_pk_f32_fp8((int)sv.y, true);
    float sf[8] = {s0[0], s0[1], s1[0], s1[1], s2[0], s2[1], s3[0], s3[1]};
    u16x8 o;
#pragma unroll
    for (int k = 0; k < 8; k++) {
        float x = fmaf(sf[k], w0, a[k]) + bias[fl * 8 + k];
        if (do_relu) x = fmaxf(x, 0.f);
        o[k] = f2bf(x);
    }
    if (half == 0)
        ((u16x8*)(out + (size_t)wid * HDIM))[fl] = o;
}

// --------------------------------------------------- bf16 MFMA GEMM 128x128
// EPI 0: raw -> fp8 C.  EPI 1: bias+relu -> bf16.  EPI 2: bias+sigmoid -> fp32.

template <int EPI>
__global__ __launch_bounds__(256) void k_gemm(const unsigned short* __restrict__ A,
                                              const unsigned short* __restrict__ Bt,
                                              const float* __restrict__ bias,
                                              void* __restrict__ Cout,
                                              int M, int K, int Nc) {
    __shared__ __align__(16) unsigned short As[128 * 32];
    __shared__ __align__(16) unsigned short Bs[128 * 32];
    int tid = threadIdx.x;
    int wid = tid >> 6, lane = tid & 63;
    int wr = wid >> 1, wc = wid & 1;
    int mb = blockIdx.y * 128, nb = blockIdx.x * 128;

    int sr = tid >> 2;
    int ssl = (tid & 3) ^ ((sr >> 1) & 3);
    int ar0 = mb + sr;      if (ar0 > M - 1) ar0 = M - 1;
    int ar1 = mb + sr + 64; if (ar1 > M - 1) ar1 = M - 1;
    const unsigned short* gA0 = A + (size_t)ar0 * K + ssl * 8;
    const unsigned short* gA1 = A + (size_t)ar1 * K + ssl * 8;
    const unsigned short* gB0 = Bt + (size_t)(nb + sr) * K + ssl * 8;
    const unsigned short* gB1 = Bt + (size_t)(nb + sr + 64) * K + ssl * 8;
    unsigned short* ldsA = As + tid * 8;
    unsigned short* ldsB = Bs + tid * 8;

    f32x4 acc[4][4];
#pragma unroll
    for (int m = 0; m < 4; m++)
#pragma unroll
        for (int n = 0; n < 4; n++) acc[m][n] = (f32x4){0.f, 0.f, 0.f, 0.f};

    int l15 = lane & 15, ks = lane >> 4;

    for (int k0 = 0; k0 < K; k0 += 32) {
        gload16(gA0 + k0, ldsA);
        gload16(gA1 + k0, ldsA + 2048);
        gload16(gB0 + k0, ldsB);
        gload16(gB1 + k0, ldsB + 2048);
        __syncthreads();

        short8 af[4], bfr[4];
#pragma unroll
        for (int m = 0; m < 4; m++) {
            int row = wr * 64 + m * 16 + l15;
            int slot = ks ^ ((row >> 1) & 3);
            af[m] = *(const short8*)((const char*)As + row * 64 + slot * 16);
        }
#pragma unroll
        for (int n = 0; n < 4; n++) {
            int row = wc * 64 + n * 16 + l15;
            int slot = ks ^ ((row >> 1) & 3);
            bfr[n] = *(const short8*)((const char*)Bs + row * 64 + slot * 16);
        }
#pragma unroll
        for (int m = 0; m < 4; m++)
#pragma unroll
            for (int n = 0; n < 4; n++)
                acc[m][n] = __builtin_amdgcn_mfma_f32_16x16x32_bf16(af[m], bfr[n], acc[m][n], 0, 0, 0);
        __syncthreads();
    }

    int lq = lane >> 4;
#pragma unroll
    for (int m = 0; m < 4; m++) {
#pragma unroll
        for (int n = 0; n < 4; n++) {
            int gcol = nb + wc * 64 + n * 16 + l15;
#pragma unroll
            for (int r = 0; r < 4; r++) {
                int grow = mb + wr * 64 + m * 16 + lq * 4 + r;
                if (grow >= M) continue;
                float v = acc[m][n][r];
                if (EPI == 0) {
                    ((unsigned char*)Cout)[(size_t)grow * Nc + gcol] = f2fp8(v);
                } else if (EPI == 1) {
                    v += bias[gcol];
                    v = fmaxf(v, 0.f);
                    ((unsigned short*)Cout)[(size_t)grow * Nc + gcol] = f2bf(v);
                } else {
                    if (gcol < Nc) {
                        v += bias[gcol];
                        v = 1.f / (1.f + expf(-v));
                        ((float*)Cout)[(size_t)grow * Nc + gcol] = v;
                    }
                }
            }
        }
    }
}

// ------------------------------------------------------------- gate fusion

__global__ void k_gate(const unsigned short* __restrict__ h1, const unsigned short* __restrict__ h2,
                       const float* __restrict__ w1, const float* __restrict__ w1b,
                       const float* __restrict__ w2, const float* __restrict__ w2b,
                       unsigned short* __restrict__ m, int n) {
    int gtid = blockIdx.x * blockDim.x + threadIdx.x;
    int wid = gtid >> 6;
    int lane = threadIdx.x & 63;
    if (wid >= n) return;
    ushort4 av = ((const ushort4*)(h1 + (size_t)wid * HDIM))[lane];
    ushort4 bv = ((const ushort4*)(h2 + (size_t)wid * HDIM))[lane];
    float4 wa = ((const float4*)w1)[lane];
    float4 wb = ((const float4*)w2)[lane];
    float a0 = bf2f(av.x), a1 = bf2f(av.y), a2 = bf2f(av.z), a3 = bf2f(av.w);
    float b0 = bf2f(bv.x), b1 = bf2f(bv.y), b2 = bf2f(bv.z), b3 = bf2f(bv.w);
    float d1 = a0 * wa.x + a1 * wa.y + a2 * wa.z + a3 * wa.w;
    float d2 = b0 * wb.x + b1 * wb.y + b2 * wb.z + b3 * wb.w;
    for (int off = 32; off > 0; off >>= 1) {
        d1 += __shfl_xor(d1, off);
        d2 += __shfl_xor(d2, off);
    }
    float f1 = 1.f / (1.f + expf(-(d1 + w1b[0])));
    float f2 = 1.f / (1.f + expf(-(d2 + w2b[0])));
    float f = f1 / (f1 + f2);
    ushort4 o;
    o.x = f2bf(f * a0 + (1.f - f) * b0);
    o.y = f2bf(f * a1 + (1.f - f) * b1);
    o.z = f2bf(f * a2 + (1.f - f) * b2);
    o.w = f2bf(f * a3 + (1.f - f) * b3);
    ((ushort4*)(m + (size_t)wid * HDIM))[lane] = o;
}

// ------------------------------------------------------------------ launch

extern "C" void kernel_launch(void* const* d_in, const int* in_sizes, int n_in,
                              void* d_out, int out_size, void* d_ws, size_t ws_size,
                              hipStream_t stream) {
    (void)n_in; (void)out_size; (void)ws_size;
    const int N = N_NODES, E = E_EDGES;

    const float* x1; const float* x2; const int* ei1; const int* ei2;
    if (in_sizes[1] == 2 * E) {
        x1 = (const float*)d_in[0]; ei1 = (const int*)d_in[1];
        x2 = (const float*)d_in[2]; ei2 = (const int*)d_in[3];
    } else {
        x1 = (const float*)d_in[0]; x2 = (const float*)d_in[1];
        ei1 = (const int*)d_in[2]; ei2 = (const int*)d_in[3];
    }
    const float* W[2][4]; const float* Bv[2][4];
    int idx = 4;
    for (int br = 0; br < 2; br++)
        for (int l = 0; l < 4; l++) {
            W[br][l] = (const float*)d_in[idx++];
            Bv[br][l] = (const float*)d_in[idx++];
        }
    const float* w1W  = (const float*)d_in[20];
    const float* w1b  = (const float*)d_in[21];
    const float* w2W  = (const float*)d_in[22];
    const float* w2b  = (const float*)d_in[23];
    const float* finW = (const float*)d_in[24];
    const float* finb = (const float*)d_in[25];
    const float* outW = (const float*)d_in[26];
    const float* outb = (const float*)d_in[27];
    float* out = (float*)d_out;

    size_t off = 0;
    auto alloc = [&](size_t bytes) {
        void* p = (char*)d_ws + off;
        off = (off + bytes + 255) & ~(size_t)255;
        return p;
    };
    unsigned short* x1b = (unsigned short*)alloc((size_t)N * F_IN * 2);  // also fin-out t
    unsigned short* x2b = (unsigned short*)alloc((size_t)N * F_IN * 2);
    unsigned char*  g8  = (unsigned char*)alloc((size_t)N * HDIM);       // fp8 GEMM out
    unsigned short* mb_ = (unsigned short*)alloc((size_t)N * HDIM * 2);
    unsigned short* h1b = (unsigned short*)alloc((size_t)N * HDIM * 2);
    unsigned short* h2b = (unsigned short*)alloc((size_t)N * HDIM * 2);
    unsigned short* Wt[2][4];
    Wt[0][0] = (unsigned short*)alloc((size_t)HDIM * F_IN * 2);
    for (int l = 1; l < 4; l++) Wt[0][l] = (unsigned short*)alloc((size_t)HDIM * HDIM * 2);
    Wt[1][0] = (unsigned short*)alloc((size_t)HDIM * F_IN * 2);
    for (int l = 1; l < 4; l++) Wt[1][l] = (unsigned short*)alloc((size_t)HDIM * HDIM * 2);
    unsigned short* finWt = (unsigned short*)alloc((size_t)HDIM * HDIM * 2);
    unsigned short* outWt = (unsigned short*)alloc((size_t)128 * HDIM * 2);
    int2* cw1   = (int2*)alloc((size_t)E * 8);
    int2* cw2   = (int2*)alloc((size_t)E * 8);
    int* rp1    = (int*)alloc((size_t)(N + 1) * 4);
    int* rp2    = (int*)alloc((size_t)(N + 1) * 4);
    int* incl1  = (int*)alloc((size_t)N * 4);
    int* incl2  = (int*)alloc((size_t)N * 4);
    int* bsum1  = (int*)alloc((size_t)256 * 4);
    int* bsum2  = (int*)alloc((size_t)256 * 4);
    int* cnt1   = (int*)alloc((size_t)N * 4);
    int* cnt2   = (int*)alloc((size_t)N * 4);
    int* cur1   = (int*)alloc((size_t)N * 4);
    int* cur2   = (int*)alloc((size_t)N * 4);
    float* di1  = (float*)alloc((size_t)N * 4);
    float* di2  = (float*)alloc((size_t)N * 4);

    const int BLK = 256;
    int nwaves_grid = (N * 64 + BLK - 1) / BLK;   // 12500
    int nchunks = (N + 255) / 256;                // 196
    int mtiles = (N + 127) / 128;                 // 391
    dim3 grid_h(HDIM / 128, mtiles);
    dim3 grid_o(1, mtiles);

    // fused weight conversion (10 transposes, outW zero-padded to 128 rows)
    WPack wp;
    wp.d[0] = {W[0][0], Wt[0][0], F_IN, HDIM, HDIM};
    wp.d[1] = {W[0][1], Wt[0][1], HDIM, HDIM, HDIM};
    wp.d[2] = {W[0][2], Wt[0][2], HDIM, HDIM, HDIM};
    wp.d[3] = {W[0][3], Wt[0][3], HDIM, HDIM, HDIM};
    wp.d[4] = {W[1][0], Wt[1][0], F_IN, HDIM, HDIM};
    wp.d[5] = {W[1][1], Wt[1][1], HDIM, HDIM, HDIM};
    wp.d[6] = {W[1][2], Wt[1][2], HDIM, HDIM, HDIM};
    wp.d[7] = {W[1][3], Wt[1][3], HDIM, HDIM, HDIM};
    wp.d[8] = {finW, finWt, HDIM, HDIM, HDIM};
    wp.d[9] = {outW, outWt, HDIM, L_OUT, 128};
    k_wconv<<<dim3(512, 10), BLK, 0, stream>>>(wp);

    // CSR build, both branches fused
    hipMemsetAsync(cnt1, 0, (size_t)N * 4, stream);
    hipMemsetAsync(cnt2, 0, (size_t)N * 4, stream);
    hipMemsetAsync(cur1, 0, (size_t)N * 4, stream);
    hipMemsetAsync(cur2, 0, (size_t)N * 4, stream);
    k_count2<<<2048, BLK, 0, stream>>>(ei1 + E, ei2 + E, cnt1, cnt2, E);
    k_scan1f<<<dim3(nchunks, 2), BLK, 0, stream>>>(cnt1, cnt2, incl1, incl2, bsum1, bsum2, N);
    k_scan2f<<<2, BLK, 0, stream>>>(bsum1, bsum2, rp1, rp2, nchunks, N);
    k_scan3f<<<dim3(nchunks, 2), BLK, 0, stream>>>(incl1, incl2, cnt1, cnt2, bsum1, bsum2, rp1, rp2, N);
    k_dinv2<<<(2 * N + BLK - 1) / BLK, BLK, 0, stream>>>(cnt1, cnt2, di1, di2, N);
    k_fill2<<<4096, BLK, 0, stream>>>(ei1, ei1 + E, ei2, ei2 + E, rp1, rp2,
                                      cur1, cur2, di1, di2, cw1, cw2, E);
    k_f2b2<<<4096, BLK, 0, stream>>>(x1, x2, x1b, x2b, N * F_IN / 4);

    // branch-sequential layers: GEMM -> agg immediately (g8 hot in L2)
    for (int br = 0; br < 2; br++) {
        const int2* cw = br ? cw2 : cw1;
        const int* rp = br ? rp2 : rp1;
        const float* di = br ? di2 : di1;
        const unsigned short* xb = br ? x2b : x1b;
        unsigned short* hb = br ? h2b : h1b;

        k_gemm<0><<<grid_h, BLK, 0, stream>>>(xb, Wt[br][0], nullptr, g8, N, F_IN, HDIM);
        k_agg<<<nwaves_grid, BLK, 0, stream>>>(g8, rp, cw, di, Bv[br][0], hb, N, 1);
        for (int l = 1; l <= 2; l++) {
            k_gemm<0><<<grid_h, BLK, 0, stream>>>(hb, Wt[br][l], nullptr, g8, N, HDIM, HDIM);
            k_agg<<<nwaves_grid, BLK, 0, stream>>>(g8, rp, cw, di, Bv[br][l], hb, N, 1);
        }
        k_gemm<0><<<grid_h, BLK, 0, stream>>>(hb, Wt[br][3], nullptr, g8, N, HDIM, HDIM);
        k_agg<<<nwaves_grid, BLK, 0, stream>>>(g8, rp, cw, di, Bv[br][3], hb, N, 0);
    }

    k_gate<<<nwaves_grid, BLK, 0, stream>>>(h1b, h2b, w1W, w1b, w2W, w2b, mb_, N);
    k_gemm<1><<<grid_h, BLK, 0, stream>>>(mb_, finWt, finb, x1b, N, HDIM, HDIM);
    k_gemm<2><<<grid_o, BLK, 0, stream>>>(x1b, outWt, outb, out, N, HDIM, L_OUT);
}

// Round 9
// 1028.892 us; speedup vs baseline: 2.0840x; 1.1146x over previous
//
#include <hip/hip_runtime.h>
#include <math.h>

#define N_NODES 50000
#define F_IN    512
#define HDIM    256
#define L_OUT   52
#define E_EDGES 1600000

typedef short short8 __attribute__((ext_vector_type(8)));
typedef unsigned short u16x8 __attribute__((ext_vector_type(8)));
typedef float f32x4 __attribute__((ext_vector_type(4)));
typedef float f32x2 __attribute__((ext_vector_type(2)));

__device__ __forceinline__ float bf2f(unsigned short u) {
    unsigned int x = ((unsigned int)u) << 16;
    return __builtin_bit_cast(float, x);
}
__device__ __forceinline__ unsigned short f2bf(float f) {
    unsigned int u = __builtin_bit_cast(unsigned int, f);
    return (unsigned short)((u + 0x7fffu + ((u >> 16) & 1u)) >> 16);
}
__device__ __forceinline__ unsigned char f2fp8(float f) {
    int pk = __builtin_amdgcn_cvt_pk_fp8_f32(f, 0.f, 0, false);
    return (unsigned char)(pk & 0xff);
}
__device__ __forceinline__ void gload16(const unsigned short* g, unsigned short* l) {
    __builtin_amdgcn_global_load_lds(
        (const __attribute__((address_space(1))) unsigned int*)(g),
        (__attribute__((address_space(3))) unsigned int*)(l), 16, 0, 0);
}

// ------------------------------------------- CSR build (both branches fused)
// rank trick: count pass also records each edge's arrival rank (coalesced
// write), so the fill pass needs NO atomics.

__global__ void k_rank2(const int* __restrict__ d1, const int* __restrict__ d2,
                        int* __restrict__ c1, int* __restrict__ c2,
                        int* __restrict__ rk1, int* __restrict__ rk2, int E) {
    int i = blockIdx.x * blockDim.x + threadIdx.x;
    int stride = gridDim.x * blockDim.x;
    int tot = 2 * E;
    for (; i < tot; i += stride) {
        if (i < E) rk1[i] = atomicAdd(&c1[d1[i]], 1);
        else       rk2[i - E] = atomicAdd(&c2[d2[i - E]], 1);
    }
}

__global__ void k_dinv2(const int* __restrict__ c1, const int* __restrict__ c2,
                        float* __restrict__ v1, float* __restrict__ v2, int n) {
    int i = blockIdx.x * blockDim.x + threadIdx.x;
    if (i < n) v1[i] = rsqrtf((float)(c1[i] + 1));
    else if (i < 2 * n) v2[i - n] = rsqrtf((float)(c2[i - n] + 1));
}

__global__ void k_scan1f(const int* __restrict__ c1, const int* __restrict__ c2,
                         int* __restrict__ i1, int* __restrict__ i2,
                         int* __restrict__ b1, int* __restrict__ b2, int n) {
    const int* cnt = blockIdx.y ? c2 : c1;
    int* incl = blockIdx.y ? i2 : i1;
    int* bsum = blockIdx.y ? b2 : b1;
    __shared__ int s[256];
    int tid = threadIdx.x;
    int idx = blockIdx.x * 256 + tid;
    int v = (idx < n) ? cnt[idx] : 0;
    s[tid] = v;
    __syncthreads();
#pragma unroll
    for (int off = 1; off < 256; off <<= 1) {
        int t = (tid >= off) ? s[tid - off] : 0;
        __syncthreads();
        s[tid] += t;
        __syncthreads();
    }
    if (idx < n) incl[idx] = s[tid];
    if (tid == 255) bsum[blockIdx.x] = s[255];
}

__global__ void k_scan2f(int* __restrict__ b1, int* __restrict__ b2,
                         int* __restrict__ r1, int* __restrict__ r2, int nb, int n) {
    int* bsum = blockIdx.x ? b2 : b1;
    int* rowptr = blockIdx.x ? r2 : r1;
    __shared__ int s[256];
    int tid = threadIdx.x;
    int v = (tid < nb) ? bsum[tid] : 0;
    s[tid] = v;
    __syncthreads();
#pragma unroll
    for (int off = 1; off < 256; off <<= 1) {
        int t = (tid >= off) ? s[tid - off] : 0;
        __syncthreads();
        s[tid] += t;
        __syncthreads();
    }
    if (tid < nb) bsum[tid] = s[tid] - v;
    if (tid == nb - 1) rowptr[n] = s[tid];
}

__global__ void k_scan3f(const int* __restrict__ i1, const int* __restrict__ i2,
                         const int* __restrict__ c1, const int* __restrict__ c2,
                         const int* __restrict__ b1, const int* __restrict__ b2,
                         int* __restrict__ r1, int* __restrict__ r2, int n) {
    const int* incl = blockIdx.y ? i2 : i1;
    const int* cnt  = blockIdx.y ? c2 : c1;
    const int* bsum = blockIdx.y ? b2 : b1;
    int* rowptr     = blockIdx.y ? r2 : r1;
    int i = blockIdx.x * blockDim.x + threadIdx.x;
    if (i < n) rowptr[i] = incl[i] - cnt[i] + bsum[i >> 8];
}

// atomic-free fill: pos = rowptr[dst] + rank[e]; store uint16 src.
// per-branch col array is 3.2MB -> L2-resident scatter, minimal writeback.
__global__ void k_fill2(const int* __restrict__ s1, const int* __restrict__ d1,
                        const int* __restrict__ s2, const int* __restrict__ d2,
                        const int* __restrict__ rk1, const int* __restrict__ rk2,
                        const int* __restrict__ rp1, const int* __restrict__ rp2,
                        unsigned short* __restrict__ col1, unsigned short* __restrict__ col2,
                        int E) {
    int i = blockIdx.x * blockDim.x + threadIdx.x;
    int stride = gridDim.x * blockDim.x;
    int tot = 2 * E;
    for (; i < tot; i += stride) {
        int br = i >= E;
        int e = br ? i - E : i;
        const int* S = br ? s2 : s1;
        const int* D = br ? d2 : d1;
        const int* RK = br ? rk2 : rk1;
        const int* RP = br ? rp2 : rp1;
        unsigned short* C = br ? col2 : col1;
        int d = D[e];
        C[RP[d] + RK[e]] = (unsigned short)S[e];
    }
}

// ------------------------------------------------------------- conversions

__global__ void k_f2b2(const float* __restrict__ x1, const float* __restrict__ x2,
                       unsigned short* __restrict__ o1, unsigned short* __restrict__ o2,
                       int n4) {
    int i = blockIdx.x * blockDim.x + threadIdx.x;
    int stride = gridDim.x * blockDim.x;
    int tot = 2 * n4;
    for (; i < tot; i += stride) {
        int br = i >= n4;
        int e = br ? i - n4 : i;
        float4 v = ((const float4*)(br ? x2 : x1))[e];
        ushort4 o;
        o.x = f2bf(v.x); o.y = f2bf(v.y); o.z = f2bf(v.z); o.w = f2bf(v.w);
        ((ushort4*)(br ? o2 : o1))[e] = o;
    }
}

// fused weight transpose: fp32 [K][N] -> bf16 [Npad][K], zero-padded rows
struct WDesc { const float* in; unsigned short* out; int K; int N; int Npad; };
struct WPack { WDesc d[10]; };

__global__ void k_wconv(WPack p) {
    WDesc w = p.d[blockIdx.y];
    int total = w.K * w.Npad;
    int idx = blockIdx.x * 256 + threadIdx.x;
    if (idx >= total) return;
    int n = idx / w.K, k = idx - n * w.K;
    w.out[idx] = (n < w.N) ? f2bf(w.in[(size_t)k * w.N + n]) : (unsigned short)0;
}

// ------- aggregation (R6 structure): wave/node, lane-halves = even/odd
//         neighbor streams, 8B fp8 row loads; weight recomputed from dinv.

__global__ void k_agg(const unsigned char* __restrict__ g, const int* __restrict__ rowptr,
                      const unsigned short* __restrict__ col,
                      const float* __restrict__ dinv,
                      const float* __restrict__ bias, unsigned short* __restrict__ out,
                      int n, int do_relu) {
    int gtid = blockIdx.x * blockDim.x + threadIdx.x;
    int wid = gtid >> 6;
    if (wid >= n) return;
    int lane = threadIdx.x & 63;
    int half = lane >> 5;   // even/odd neighbor stream
    int fl = lane & 31;     // feature group: 8 fp8 = 8B

    float di = dinv[wid];

    float a[8];
#pragma unroll
    for (int k = 0; k < 8; k++) a[k] = 0.f;

    int r0 = rowptr[wid], r1 = rowptr[wid + 1];

    int base = r0;
    for (; base + 16 <= r1; base += 16) {
        int c[8]; float w[8]; uint2 v[8];
#pragma unroll
        for (int t = 0; t < 8; t++) c[t] = col[base + 2 * t + half];
#pragma unroll
        for (int t = 0; t < 8; t++) w[t] = dinv[c[t]];
#pragma unroll
        for (int t = 0; t < 8; t++)
            v[t] = ((const uint2*)(g + (size_t)c[t] * HDIM))[fl];
#pragma unroll
        for (int t = 0; t < 8; t++) {
            float wt = w[t] * di;
            f32x2 p0 = __builtin_amdgcn_cvt_pk_f32_fp8((int)v[t].x, false);
            f32x2 p1 = __builtin_amdgcn_cvt_pk_f32_fp8((int)v[t].x, true);
            f32x2 p2 = __builtin_amdgcn_cvt_pk_f32_fp8((int)v[t].y, false);
            f32x2 p3 = __builtin_amdgcn_cvt_pk_f32_fp8((int)v[t].y, true);
            a[0] = fmaf(p0[0], wt, a[0]); a[1] = fmaf(p0[1], wt, a[1]);
            a[2] = fmaf(p1[0], wt, a[2]); a[3] = fmaf(p1[1], wt, a[3]);
            a[4] = fmaf(p2[0], wt, a[4]); a[5] = fmaf(p2[1], wt, a[5]);
            a[6] = fmaf(p3[0], wt, a[6]); a[7] = fmaf(p3[1], wt, a[7]);
        }
    }
    if (base < r1) {  // remainder 1..15 neighbors, zero-weight padding
        int c[8]; float w[8]; uint2 v[8];
#pragma unroll
        for (int t = 0; t < 8; t++) {
            int idx = base + 2 * t + half;
            int ok = idx < r1;
            c[t] = col[ok ? idx : r0];
            w[t] = ok ? dinv[c[t]] : 0.f;
        }
#pragma unroll
        for (int t = 0; t < 8; t++)
            v[t] = ((const uint2*)(g + (size_t)c[t] * HDIM))[fl];
#pragma unroll
        for (int t = 0; t < 8; t++) {
            float wt = w[t] * di;
            f32x2 p0 = __builtin_amdgcn_cvt_pk_f32_fp8((int)v[t].x, false);
            f32x2 p1 = __builtin_amdgcn_cvt_pk_f32_fp8((int)v[t].x, true);
            f32x2 p2 = __builtin_amdgcn_cvt_pk_f32_fp8((int)v[t].y, false);
            f32x2 p3 = __builtin_amdgcn_cvt_pk_f32_fp8((int)v[t].y, true);
            a[0] = fmaf(p0[0], wt, a[0]); a[1] = fmaf(p0[1], wt, a[1]);
            a[2] = fmaf(p1[0], wt, a[2]); a[3] = fmaf(p1[1], wt, a[3]);
            a[4] = fmaf(p2[0], wt, a[4]); a[5] = fmaf(p2[1], wt, a[5]);
            a[6] = fmaf(p3[0], wt, a[6]); a[7] = fmaf(p3[1], wt, a[7]);
        }
    }

    // combine even/odd partial sums
#pragma unroll
    for (int k = 0; k < 8; k++) a[k] += __shfl_xor(a[k], 32);

    // self-loop + bias + activation (redundant on both halves, store once)
    float w0 = di * di;
    uint2 sv = ((const uint2*)(g + (size_t)wid * HDIM))[fl];
    f32x2 s0 = __builtin_amdgcn_cvt_pk_f32_fp8((int)sv.x, false);
    f32x2 s1 = __builtin_amdgcn_cvt_pk_f32_fp8((int)sv.x, true);
    f32x2 s2 = __builtin_amdgcn_cvt_pk_f32_fp8((int)sv.y, false);
    f32x2 s3 = __builtin_amdgcn_cvt_pk_f32_fp8((int)sv.y, true);
    float sf[8] = {s0[0], s0[1], s1[0], s1[1], s2[0], s2[1], s3[0], s3[1]};
    u16x8 o;
#pragma unroll
    for (int k = 0; k < 8; k++) {
        float x = fmaf(sf[k], w0, a[k]) + bias[fl * 8 + k];
        if (do_relu) x = fmaxf(x, 0.f);
        o[k] = f2bf(x);
    }
    if (half == 0)
        ((u16x8*)(out + (size_t)wid * HDIM))[fl] = o;
}

// --------------------------------------------------- bf16 MFMA GEMM 128x128
// EPI 0: raw -> fp8 C.  EPI 1: bias+relu -> bf16.  EPI 2: bias+sigmoid -> fp32.

template <int EPI>
__global__ __launch_bounds__(256) void k_gemm(const unsigned short* __restrict__ A,
                                              const unsigned short* __restrict__ Bt,
                                              const float* __restrict__ bias,
                                              void* __restrict__ Cout,
                                              int M, int K, int Nc) {
    __shared__ __align__(16) unsigned short As[128 * 32];
    __shared__ __align__(16) unsigned short Bs[128 * 32];
    int tid = threadIdx.x;
    int wid = tid >> 6, lane = tid & 63;
    int wr = wid >> 1, wc = wid & 1;
    int mb = blockIdx.y * 128, nb = blockIdx.x * 128;

    int sr = tid >> 2;
    int ssl = (tid & 3) ^ ((sr >> 1) & 3);
    int ar0 = mb + sr;      if (ar0 > M - 1) ar0 = M - 1;
    int ar1 = mb + sr + 64; if (ar1 > M - 1) ar1 = M - 1;
    const unsigned short* gA0 = A + (size_t)ar0 * K + ssl * 8;
    const unsigned short* gA1 = A + (size_t)ar1 * K + ssl * 8;
    const unsigned short* gB0 = Bt + (size_t)(nb + sr) * K + ssl * 8;
    const unsigned short* gB1 = Bt + (size_t)(nb + sr + 64) * K + ssl * 8;
    unsigned short* ldsA = As + tid * 8;
    unsigned short* ldsB = Bs + tid * 8;

    f32x4 acc[4][4];
#pragma unroll
    for (int m = 0; m < 4; m++)
#pragma unroll
        for (int n = 0; n < 4; n++) acc[m][n] = (f32x4){0.f, 0.f, 0.f, 0.f};

    int l15 = lane & 15, ks = lane >> 4;

    for (int k0 = 0; k0 < K; k0 += 32) {
        gload16(gA0 + k0, ldsA);
        gload16(gA1 + k0, ldsA + 2048);
        gload16(gB0 + k0, ldsB);
        gload16(gB1 + k0, ldsB + 2048);
        __syncthreads();

        short8 af[4], bfr[4];
#pragma unroll
        for (int m = 0; m < 4; m++) {
            int row = wr * 64 + m * 16 + l15;
            int slot = ks ^ ((row >> 1) & 3);
            af[m] = *(const short8*)((const char*)As + row * 64 + slot * 16);
        }
#pragma unroll
        for (int n = 0; n < 4; n++) {
            int row = wc * 64 + n * 16 + l15;
            int slot = ks ^ ((row >> 1) & 3);
            bfr[n] = *(const short8*)((const char*)Bs + row * 64 + slot * 16);
        }
#pragma unroll
        for (int m = 0; m < 4; m++)
#pragma unroll
            for (int n = 0; n < 4; n++)
                acc[m][n] = __builtin_amdgcn_mfma_f32_16x16x32_bf16(af[m], bfr[n], acc[m][n], 0, 0, 0);
        __syncthreads();
    }

    int lq = lane >> 4;
#pragma unroll
    for (int m = 0; m < 4; m++) {
#pragma unroll
        for (int n = 0; n < 4; n++) {
            int gcol = nb + wc * 64 + n * 16 + l15;
#pragma unroll
            for (int r = 0; r < 4; r++) {
                int grow = mb + wr * 64 + m * 16 + lq * 4 + r;
                if (grow >= M) continue;
                float v = acc[m][n][r];
                if (EPI == 0) {
                    ((unsigned char*)Cout)[(size_t)grow * Nc + gcol] = f2fp8(v);
                } else if (EPI == 1) {
                    v += bias[gcol];
                    v = fmaxf(v, 0.f);
                    ((unsigned short*)Cout)[(size_t)grow * Nc + gcol] = f2bf(v);
                } else {
                    if (gcol < Nc) {
                        v += bias[gcol];
                        v = 1.f / (1.f + expf(-v));
                        ((float*)Cout)[(size_t)grow * Nc + gcol] = v;
                    }
                }
            }
        }
    }
}

// ------------------------------------------------------------- gate fusion

__global__ void k_gate(const unsigned short* __restrict__ h1, const unsigned short* __restrict__ h2,
                       const float* __restrict__ w1, const float* __restrict__ w1b,
                       const float* __restrict__ w2, const float* __restrict__ w2b,
                       unsigned short* __restrict__ m, int n) {
    int gtid = blockIdx.x * blockDim.x + threadIdx.x;
    int wid = gtid >> 6;
    int lane = threadIdx.x & 63;
    if (wid >= n) return;
    ushort4 av = ((const ushort4*)(h1 + (size_t)wid * HDIM))[lane];
    ushort4 bv = ((const ushort4*)(h2 + (size_t)wid * HDIM))[lane];
    float4 wa = ((const float4*)w1)[lane];
    float4 wb = ((const float4*)w2)[lane];
    float a0 = bf2f(av.x), a1 = bf2f(av.y), a2 = bf2f(av.z), a3 = bf2f(av.w);
    float b0 = bf2f(bv.x), b1 = bf2f(bv.y), b2 = bf2f(bv.z), b3 = bf2f(bv.w);
    float d1 = a0 * wa.x + a1 * wa.y + a2 * wa.z + a3 * wa.w;
    float d2 = b0 * wb.x + b1 * wb.y + b2 * wb.z + b3 * wb.w;
    for (int off = 32; off > 0; off >>= 1) {
        d1 += __shfl_xor(d1, off);
        d2 += __shfl_xor(d2, off);
    }
    float f1 = 1.f / (1.f + expf(-(d1 + w1b[0])));
    float f2 = 1.f / (1.f + expf(-(d2 + w2b[0])));
    float f = f1 / (f1 + f2);
    ushort4 o;
    o.x = f2bf(f * a0 + (1.f - f) * b0);
    o.y = f2bf(f * a1 + (1.f - f) * b1);
    o.z = f2bf(f * a2 + (1.f - f) * b2);
    o.w = f2bf(f * a3 + (1.f - f) * b3);
    ((ushort4*)(m + (size_t)wid * HDIM))[lane] = o;
}

// ------------------------------------------------------------------ launch

extern "C" void kernel_launch(void* const* d_in, const int* in_sizes, int n_in,
                              void* d_out, int out_size, void* d_ws, size_t ws_size,
                              hipStream_t stream) {
    (void)n_in; (void)out_size; (void)ws_size;
    const int N = N_NODES, E = E_EDGES;

    const float* x1; const float* x2; const int* ei1; const int* ei2;
    if (in_sizes[1] == 2 * E) {
        x1 = (const float*)d_in[0]; ei1 = (const int*)d_in[1];
        x2 = (const float*)d_in[2]; ei2 = (const int*)d_in[3];
    } else {
        x1 = (const float*)d_in[0]; x2 = (const float*)d_in[1];
        ei1 = (const int*)d_in[2]; ei2 = (const int*)d_in[3];
    }
    const float* W[2][4]; const float* Bv[2][4];
    int idx = 4;
    for (int br = 0; br < 2; br++)
        for (int l = 0; l < 4; l++) {
            W[br][l] = (const float*)d_in[idx++];
            Bv[br][l] = (const float*)d_in[idx++];
        }
    const float* w1W  = (const float*)d_in[20];
    const float* w1b  = (const float*)d_in[21];
    const float* w2W  = (const float*)d_in[22];
    const float* w2b  = (const float*)d_in[23];
    const float* finW = (const float*)d_in[24];
    const float* finb = (const float*)d_in[25];
    const float* outW = (const float*)d_in[26];
    const float* outb = (const float*)d_in[27];
    float* out = (float*)d_out;

    size_t off = 0;
    auto alloc = [&](size_t bytes) {
        void* p = (char*)d_ws + off;
        off = (off + bytes + 255) & ~(size_t)255;
        return p;
    };
    unsigned short* x1b = (unsigned short*)alloc((size_t)N * F_IN * 2);  // also fin-out t
    unsigned short* x2b = (unsigned short*)alloc((size_t)N * F_IN * 2);
    unsigned char*  g8  = (unsigned char*)alloc((size_t)N * HDIM);       // fp8 GEMM out
    unsigned short* mb_ = (unsigned short*)alloc((size_t)N * HDIM * 2);
    unsigned short* h1b = (unsigned short*)alloc((size_t)N * HDIM * 2);
    unsigned short* h2b = (unsigned short*)alloc((size_t)N * HDIM * 2);
    unsigned short* Wt[2][4];
    Wt[0][0] = (unsigned short*)alloc((size_t)HDIM * F_IN * 2);
    for (int l = 1; l < 4; l++) Wt[0][l] = (unsigned short*)alloc((size_t)HDIM * HDIM * 2);
    Wt[1][0] = (unsigned short*)alloc((size_t)HDIM * F_IN * 2);
    for (int l = 1; l < 4; l++) Wt[1][l] = (unsigned short*)alloc((size_t)HDIM * HDIM * 2);
    unsigned short* finWt = (unsigned short*)alloc((size_t)HDIM * HDIM * 2);
    unsigned short* outWt = (unsigned short*)alloc((size_t)128 * HDIM * 2);
    unsigned short* col1 = (unsigned short*)alloc((size_t)E * 2);
    unsigned short* col2 = (unsigned short*)alloc((size_t)E * 2);
    int* rank1  = (int*)alloc((size_t)E * 4);
    int* rank2  = (int*)alloc((size_t)E * 4);
    int* rp1    = (int*)alloc((size_t)(N + 1) * 4);
    int* rp2    = (int*)alloc((size_t)(N + 1) * 4);
    int* incl1  = (int*)alloc((size_t)N * 4);
    int* incl2  = (int*)alloc((size_t)N * 4);
    int* bsum1  = (int*)alloc((size_t)256 * 4);
    int* bsum2  = (int*)alloc((size_t)256 * 4);
    int* cnt1   = (int*)alloc((size_t)N * 4);
    int* cnt2   = (int*)alloc((size_t)N * 4);
    float* di1  = (float*)alloc((size_t)N * 4);
    float* di2  = (float*)alloc((size_t)N * 4);

    const int BLK = 256;
    int nwaves_grid = (N * 64 + BLK - 1) / BLK;   // 12500
    int nchunks = (N + 255) / 256;                // 196
    int mtiles = (N + 127) / 128;                 // 391
    dim3 grid_h(HDIM / 128, mtiles);
    dim3 grid_o(1, mtiles);

    // fused weight conversion (10 transposes, outW zero-padded to 128 rows)
    WPack wp;
    wp.d[0] = {W[0][0], Wt[0][0], F_IN, HDIM, HDIM};
    wp.d[1] = {W[0][1], Wt[0][1], HDIM, HDIM, HDIM};
    wp.d[2] = {W[0][2], Wt[0][2], HDIM, HDIM, HDIM};
    wp.d[3] = {W[0][3], Wt[0][3], HDIM, HDIM, HDIM};
    wp.d[4] = {W[1][0], Wt[1][0], F_IN, HDIM, HDIM};
    wp.d[5] = {W[1][1], Wt[1][1], HDIM, HDIM, HDIM};
    wp.d[6] = {W[1][2], Wt[1][2], HDIM, HDIM, HDIM};
    wp.d[7] = {W[1][3], Wt[1][3], HDIM, HDIM, HDIM};
    wp.d[8] = {finW, finWt, HDIM, HDIM, HDIM};
    wp.d[9] = {outW, outWt, HDIM, L_OUT, 128};
    k_wconv<<<dim3(512, 10), BLK, 0, stream>>>(wp);

    // CSR build, both branches fused, rank trick
    hipMemsetAsync(cnt1, 0, (size_t)N * 4, stream);
    hipMemsetAsync(cnt2, 0, (size_t)N * 4, stream);
    k_rank2<<<2048, BLK, 0, stream>>>(ei1 + E, ei2 + E, cnt1, cnt2, rank1, rank2, E);
    k_scan1f<<<dim3(nchunks, 2), BLK, 0, stream>>>(cnt1, cnt2, incl1, incl2, bsum1, bsum2, N);
    k_scan2f<<<2, BLK, 0, stream>>>(bsum1, bsum2, rp1, rp2, nchunks, N);
    k_scan3f<<<dim3(nchunks, 2), BLK, 0, stream>>>(incl1, incl2, cnt1, cnt2, bsum1, bsum2, rp1, rp2, N);
    k_dinv2<<<(2 * N + BLK - 1) / BLK, BLK, 0, stream>>>(cnt1, cnt2, di1, di2, N);
    k_fill2<<<4096, BLK, 0, stream>>>(ei1, ei1 + E, ei2, ei2 + E, rank1, rank2,
                                      rp1, rp2, col1, col2, E);
    k_f2b2<<<4096, BLK, 0, stream>>>(x1, x2, x1b, x2b, N * F_IN / 4);

    // branch-sequential layers: GEMM -> agg immediately (g8 hot in L2)
    for (int br = 0; br < 2; br++) {
        const unsigned short* col = br ? col2 : col1;
        const int* rp = br ? rp2 : rp1;
        const float* di = br ? di2 : di1;
        const unsigned short* xb = br ? x2b : x1b;
        unsigned short* hb = br ? h2b : h1b;

        k_gemm<0><<<grid_h, BLK, 0, stream>>>(xb, Wt[br][0], nullptr, g8, N, F_IN, HDIM);
        k_agg<<<nwaves_grid, BLK, 0, stream>>>(g8, rp, col, di, Bv[br][0], hb, N, 1);
        for (int l = 1; l <= 2; l++) {
            k_gemm<0><<<grid_h, BLK, 0, stream>>>(hb, Wt[br][l], nullptr, g8, N, HDIM, HDIM);
            k_agg<<<nwaves_grid, BLK, 0, stream>>>(g8, rp, col, di, Bv[br][l], hb, N, 1);
        }
        k_gemm<0><<<grid_h, BLK, 0, stream>>>(hb, Wt[br][3], nullptr, g8, N, HDIM, HDIM);
        k_agg<<<nwaves_grid, BLK, 0, stream>>>(g8, rp, col, di, Bv[br][3], hb, N, 0);
    }

    k_gate<<<nwaves_grid, BLK, 0, stream>>>(h1b, h2b, w1W, w1b, w2W, w2b, mb_, N);
    k_gemm<1><<<grid_h, BLK, 0, stream>>>(mb_, finWt, finb, x1b, N, HDIM, HDIM);
    k_gemm<2><<<grid_o, BLK, 0, stream>>>(x1b, outWt, outb, out, N, HDIM, L_OUT);
}

// Round 10
// 993.040 us; speedup vs baseline: 2.1593x; 1.0361x over previous
//
#include <hip/hip_runtime.h>
#include <math.h>

#define N_NODES 50000
#define F_IN    512
#define HDIM    256
#define L_OUT   52
#define E_EDGES 1600000

typedef short short8 __attribute__((ext_vector_type(8)));
typedef unsigned short u16x8 __attribute__((ext_vector_type(8)));
typedef float f32x4 __attribute__((ext_vector_type(4)));
typedef float f32x2 __attribute__((ext_vector_type(2)));

__device__ __forceinline__ float bf2f(unsigned short u) {
    unsigned int x = ((unsigned int)u) << 16;
    return __builtin_bit_cast(float, x);
}
__device__ __forceinline__ unsigned short f2bf(float f) {
    unsigned int u = __builtin_bit_cast(unsigned int, f);
    return (unsigned short)((u + 0x7fffu + ((u >> 16) & 1u)) >> 16);
}
__device__ __forceinline__ unsigned char f2fp8(float f) {
    int pk = __builtin_amdgcn_cvt_pk_fp8_f32(f, 0.f, 0, false);
    return (unsigned char)(pk & 0xff);
}
__device__ __forceinline__ void gload16(const unsigned short* g, unsigned short* l) {
    __builtin_amdgcn_global_load_lds(
        (const __attribute__((address_space(1))) unsigned int*)(g),
        (__attribute__((address_space(3))) unsigned int*)(l), 16, 0, 0);
}

// ------------------------------------------- CSR build (both branches fused)
// rank trick + 8-edge batching: 8 independent atomics in flight per thread.

__global__ void k_rank2(const int* __restrict__ d1, const int* __restrict__ d2,
                        int* __restrict__ c1, int* __restrict__ c2,
                        int* __restrict__ rk1, int* __restrict__ rk2, int E) {
    int tid = blockIdx.x * blockDim.x + threadIdx.x;
    int half = E >> 3;                 // threads per branch (E % 8 == 0)
    if (tid >= 2 * half) return;
    int br = tid >= half;
    const int* D = br ? d2 : d1;
    int* C = br ? c2 : c1;
    int* RK = br ? rk2 : rk1;
    int e = (br ? tid - half : tid) << 3;
    int4 da = ((const int4*)(D + e))[0];
    int4 db = ((const int4*)(D + e))[1];
    int r0 = atomicAdd(&C[da.x], 1);
    int r1 = atomicAdd(&C[da.y], 1);
    int r2 = atomicAdd(&C[da.z], 1);
    int r3 = atomicAdd(&C[da.w], 1);
    int r4 = atomicAdd(&C[db.x], 1);
    int r5 = atomicAdd(&C[db.y], 1);
    int r6 = atomicAdd(&C[db.z], 1);
    int r7 = atomicAdd(&C[db.w], 1);
    ((int4*)(RK + e))[0] = make_int4(r0, r1, r2, r3);
    ((int4*)(RK + e))[1] = make_int4(r4, r5, r6, r7);
}

__global__ void k_dinv2(const int* __restrict__ c1, const int* __restrict__ c2,
                        float* __restrict__ v1, float* __restrict__ v2, int n) {
    int i = blockIdx.x * blockDim.x + threadIdx.x;
    if (i < n) v1[i] = rsqrtf((float)(c1[i] + 1));
    else if (i < 2 * n) v2[i - n] = rsqrtf((float)(c2[i - n] + 1));
}

__global__ void k_scan1f(const int* __restrict__ c1, const int* __restrict__ c2,
                         int* __restrict__ i1, int* __restrict__ i2,
                         int* __restrict__ b1, int* __restrict__ b2, int n) {
    const int* cnt = blockIdx.y ? c2 : c1;
    int* incl = blockIdx.y ? i2 : i1;
    int* bsum = blockIdx.y ? b2 : b1;
    __shared__ int s[256];
    int tid = threadIdx.x;
    int idx = blockIdx.x * 256 + tid;
    int v = (idx < n) ? cnt[idx] : 0;
    s[tid] = v;
    __syncthreads();
#pragma unroll
    for (int off = 1; off < 256; off <<= 1) {
        int t = (tid >= off) ? s[tid - off] : 0;
        __syncthreads();
        s[tid] += t;
        __syncthreads();
    }
    if (idx < n) incl[idx] = s[tid];
    if (tid == 255) bsum[blockIdx.x] = s[255];
}

__global__ void k_scan2f(int* __restrict__ b1, int* __restrict__ b2,
                         int* __restrict__ r1, int* __restrict__ r2, int nb, int n) {
    int* bsum = blockIdx.x ? b2 : b1;
    int* rowptr = blockIdx.x ? r2 : r1;
    __shared__ int s[256];
    int tid = threadIdx.x;
    int v = (tid < nb) ? bsum[tid] : 0;
    s[tid] = v;
    __syncthreads();
#pragma unroll
    for (int off = 1; off < 256; off <<= 1) {
        int t = (tid >= off) ? s[tid - off] : 0;
        __syncthreads();
        s[tid] += t;
        __syncthreads();
    }
    if (tid < nb) bsum[tid] = s[tid] - v;
    if (tid == nb - 1) rowptr[n] = s[tid];
}

__global__ void k_scan3f(const int* __restrict__ i1, const int* __restrict__ i2,
                         const int* __restrict__ c1, const int* __restrict__ c2,
                         const int* __restrict__ b1, const int* __restrict__ b2,
                         int* __restrict__ r1, int* __restrict__ r2, int n) {
    const int* incl = blockIdx.y ? i2 : i1;
    const int* cnt  = blockIdx.y ? c2 : c1;
    const int* bsum = blockIdx.y ? b2 : b1;
    int* rowptr     = blockIdx.y ? r2 : r1;
    int i = blockIdx.x * blockDim.x + threadIdx.x;
    if (i < n) rowptr[i] = incl[i] - cnt[i] + bsum[i >> 8];
}

// atomic-free fill, 8-edge batch: 8 independent rp gathers + u16 scatters.
__global__ void k_fill2(const int* __restrict__ s1, const int* __restrict__ d1,
                        const int* __restrict__ s2, const int* __restrict__ d2,
                        const int* __restrict__ rk1, const int* __restrict__ rk2,
                        const int* __restrict__ rp1, const int* __restrict__ rp2,
                        unsigned short* __restrict__ col1, unsigned short* __restrict__ col2,
                        int E) {
    int tid = blockIdx.x * blockDim.x + threadIdx.x;
    int half = E >> 3;
    if (tid >= 2 * half) return;
    int br = tid >= half;
    const int* S = br ? s2 : s1;
    const int* D = br ? d2 : d1;
    const int* RK = br ? rk2 : rk1;
    const int* RP = br ? rp2 : rp1;
    unsigned short* C = br ? col2 : col1;
    int e = (br ? tid - half : tid) << 3;
    int4 da = ((const int4*)(D + e))[0];
    int4 db = ((const int4*)(D + e))[1];
    int4 sa = ((const int4*)(S + e))[0];
    int4 sb = ((const int4*)(S + e))[1];
    int4 ra = ((const int4*)(RK + e))[0];
    int4 rb = ((const int4*)(RK + e))[1];
    int p0 = RP[da.x] + ra.x;
    int p1 = RP[da.y] + ra.y;
    int p2 = RP[da.z] + ra.z;
    int p3 = RP[da.w] + ra.w;
    int p4 = RP[db.x] + rb.x;
    int p5 = RP[db.y] + rb.y;
    int p6 = RP[db.z] + rb.z;
    int p7 = RP[db.w] + rb.w;
    C[p0] = (unsigned short)sa.x;
    C[p1] = (unsigned short)sa.y;
    C[p2] = (unsigned short)sa.z;
    C[p3] = (unsigned short)sa.w;
    C[p4] = (unsigned short)sb.x;
    C[p5] = (unsigned short)sb.y;
    C[p6] = (unsigned short)sb.z;
    C[p7] = (unsigned short)sb.w;
}

// ------------------------------------------------------------- conversions

__global__ void k_f2b2(const float* __restrict__ x1, const float* __restrict__ x2,
                       unsigned short* __restrict__ o1, unsigned short* __restrict__ o2,
                       int n4) {
    int i = blockIdx.x * blockDim.x + threadIdx.x;
    int stride = gridDim.x * blockDim.x;
    int tot = 2 * n4;
    for (; i < tot; i += stride) {
        int br = i >= n4;
        int e = br ? i - n4 : i;
        float4 v = ((const float4*)(br ? x2 : x1))[e];
        ushort4 o;
        o.x = f2bf(v.x); o.y = f2bf(v.y); o.z = f2bf(v.z); o.w = f2bf(v.w);
        ((ushort4*)(br ? o2 : o1))[e] = o;
    }
}

// fused weight transpose: fp32 [K][N] -> bf16 [Npad][K], zero-padded rows
struct WDesc { const float* in; unsigned short* out; int K; int N; int Npad; };
struct WPack { WDesc d[10]; };

__global__ void k_wconv(WPack p) {
    WDesc w = p.d[blockIdx.y];
    int total = w.K * w.Npad;
    int idx = blockIdx.x * 256 + threadIdx.x;
    if (idx >= total) return;
    int n = idx / w.K, k = idx - n * w.K;
    w.out[idx] = (n < w.N) ? f2bf(w.in[(size_t)k * w.N + n]) : (unsigned short)0;
}

// ------- aggregation (R6 structure): wave/node, lane-halves = even/odd
//         neighbor streams, 8B fp8 row loads; weight recomputed from dinv.

__global__ void k_agg(const unsigned char* __restrict__ g, const int* __restrict__ rowptr,
                      const unsigned short* __restrict__ col,
                      const float* __restrict__ dinv,
                      const float* __restrict__ bias, unsigned short* __restrict__ out,
                      int n, int do_relu) {
    int gtid = blockIdx.x * blockDim.x + threadIdx.x;
    int wid = gtid >> 6;
    if (wid >= n) return;
    int lane = threadIdx.x & 63;
    int half = lane >> 5;   // even/odd neighbor stream
    int fl = lane & 31;     // feature group: 8 fp8 = 8B

    float di = dinv[wid];

    float a[8];
#pragma unroll
    for (int k = 0; k < 8; k++) a[k] = 0.f;

    int r0 = rowptr[wid], r1 = rowptr[wid + 1];

    int base = r0;
    for (; base + 16 <= r1; base += 16) {
        int c[8]; float w[8]; uint2 v[8];
#pragma unroll
        for (int t = 0; t < 8; t++) c[t] = col[base + 2 * t + half];
#pragma unroll
        for (int t = 0; t < 8; t++) w[t] = dinv[c[t]];
#pragma unroll
        for (int t = 0; t < 8; t++)
            v[t] = ((const uint2*)(g + (size_t)c[t] * HDIM))[fl];
#pragma unroll
        for (int t = 0; t < 8; t++) {
            float wt = w[t] * di;
            f32x2 p0 = __builtin_amdgcn_cvt_pk_f32_fp8((int)v[t].x, false);
            f32x2 p1 = __builtin_amdgcn_cvt_pk_f32_fp8((int)v[t].x, true);
            f32x2 p2 = __builtin_amdgcn_cvt_pk_f32_fp8((int)v[t].y, false);
            f32x2 p3 = __builtin_amdgcn_cvt_pk_f32_fp8((int)v[t].y, true);
            a[0] = fmaf(p0[0], wt, a[0]); a[1] = fmaf(p0[1], wt, a[1]);
            a[2] = fmaf(p1[0], wt, a[2]); a[3] = fmaf(p1[1], wt, a[3]);
            a[4] = fmaf(p2[0], wt, a[4]); a[5] = fmaf(p2[1], wt, a[5]);
            a[6] = fmaf(p3[0], wt, a[6]); a[7] = fmaf(p3[1], wt, a[7]);
        }
    }
    if (base < r1) {  // remainder 1..15 neighbors, zero-weight padding
        int c[8]; float w[8]; uint2 v[8];
#pragma unroll
        for (int t = 0; t < 8; t++) {
            int idx = base + 2 * t + half;
            int ok = idx < r1;
            c[t] = col[ok ? idx : r0];
            w[t] = ok ? dinv[c[t]] : 0.f;
        }
#pragma unroll
        for (int t = 0; t < 8; t++)
            v[t] = ((const uint2*)(g + (size_t)c[t] * HDIM))[fl];
#pragma unroll
        for (int t = 0; t < 8; t++) {
            float wt = w[t] * di;
            f32x2 p0 = __builtin_amdgcn_cvt_pk_f32_fp8((int)v[t].x, false);
            f32x2 p1 = __builtin_amdgcn_cvt_pk_f32_fp8((int)v[t].x, true);
            f32x2 p2 = __builtin_amdgcn_cvt_pk_f32_fp8((int)v[t].y, false);
            f32x2 p3 = __builtin_amdgcn_cvt_pk_f32_fp8((int)v[t].y, true);
            a[0] = fmaf(p0[0], wt, a[0]); a[1] = fmaf(p0[1], wt, a[1]);
            a[2] = fmaf(p1[0], wt, a[2]); a[3] = fmaf(p1[1], wt, a[3]);
            a[4] = fmaf(p2[0], wt, a[4]); a[5] = fmaf(p2[1], wt, a[5]);
            a[6] = fmaf(p3[0], wt, a[6]); a[7] = fmaf(p3[1], wt, a[7]);
        }
    }

    // combine even/odd partial sums
#pragma unroll
    for (int k = 0; k < 8; k++) a[k] += __shfl_xor(a[k], 32);

    // self-loop + bias + activation (redundant on both halves, store once)
    float w0 = di * di;
    uint2 sv = ((const uint2*)(g + (size_t)wid * HDIM))[fl];
    f32x2 s0 = __builtin_amdgcn_cvt_pk_f32_fp8((int)sv.x, false);
    f32x2 s1 = __builtin_amdgcn_cvt_pk_f32_fp8((int)sv.x, true);
    f32x2 s2 = __builtin_amdgcn_cvt_pk_f32_fp8((int)sv.y, false);
    f32x2 s3 = __builtin_amdgcn_cvt_pk_f32_fp8((int)sv.y, true);
    float sf[8] = {s0[0], s0[1], s1[0], s1[1], s2[0], s2[1], s3[0], s3[1]};
    u16x8 o;
#pragma unroll
    for (int k = 0; k < 8; k++) {
        float x = fmaf(sf[k], w0, a[k]) + bias[fl * 8 + k];
        if (do_relu) x = fmaxf(x, 0.f);
        o[k] = f2bf(x);
    }
    if (half == 0)
        ((u16x8*)(out + (size_t)wid * HDIM))[fl] = o;
}

// --------------------------------------------------- bf16 MFMA GEMM 128x128
// EPI 0: raw -> fp8 C.  EPI 1: bias+relu -> bf16.  EPI 2: bias+sigmoid -> fp32.

template <int EPI>
__global__ __launch_bounds__(256) void k_gemm(const unsigned short* __restrict__ A,
                                              const unsigned short* __restrict__ Bt,
                                              const float* __restrict__ bias,
                                              void* __restrict__ Cout,
                                              int M, int K, int Nc) {
    __shared__ __align__(16) unsigned short As[128 * 32];
    __shared__ __align__(16) unsigned short Bs[128 * 32];
    int tid = threadIdx.x;
    int wid = tid >> 6, lane = tid & 63;
    int wr = wid >> 1, wc = wid & 1;
    int mb = blockIdx.y * 128, nb = blockIdx.x * 128;

    int sr = tid >> 2;
    int ssl = (tid & 3) ^ ((sr >> 1) & 3);
    int ar0 = mb + sr;      if (ar0 > M - 1) ar0 = M - 1;
    int ar1 = mb + sr + 64; if (ar1 > M - 1) ar1 = M - 1;
    const unsigned short* gA0 = A + (size_t)ar0 * K + ssl * 8;
    const unsigned short* gA1 = A + (size_t)ar1 * K + ssl * 8;
    const unsigned short* gB0 = Bt + (size_t)(nb + sr) * K + ssl * 8;
    const unsigned short* gB1 = Bt + (size_t)(nb + sr + 64) * K + ssl * 8;
    unsigned short* ldsA = As + tid * 8;
    unsigned short* ldsB = Bs + tid * 8;

    f32x4 acc[4][4];
#pragma unroll
    for (int m = 0; m < 4; m++)
#pragma unroll
        for (int n = 0; n < 4; n++) acc[m][n] = (f32x4){0.f, 0.f, 0.f, 0.f};

    int l15 = lane & 15, ks = lane >> 4;

    for (int k0 = 0; k0 < K; k0 += 32) {
        gload16(gA0 + k0, ldsA);
        gload16(gA1 + k0, ldsA + 2048);
        gload16(gB0 + k0, ldsB);
        gload16(gB1 + k0, ldsB + 2048);
        __syncthreads();

        short8 af[4], bfr[4];
#pragma unroll
        for (int m = 0; m < 4; m++) {
            int row = wr * 64 + m * 16 + l15;
            int slot = ks ^ ((row >> 1) & 3);
            af[m] = *(const short8*)((const char*)As + row * 64 + slot * 16);
        }
#pragma unroll
        for (int n = 0; n < 4; n++) {
            int row = wc * 64 + n * 16 + l15;
            int slot = ks ^ ((row >> 1) & 3);
            bfr[n] = *(const short8*)((const char*)Bs + row * 64 + slot * 16);
        }
#pragma unroll
        for (int m = 0; m < 4; m++)
#pragma unroll
            for (int n = 0; n < 4; n++)
                acc[m][n] = __builtin_amdgcn_mfma_f32_16x16x32_bf16(af[m], bfr[n], acc[m][n], 0, 0, 0);
        __syncthreads();
    }

    int lq = lane >> 4;
#pragma unroll
    for (int m = 0; m < 4; m++) {
#pragma unroll
        for (int n = 0; n < 4; n++) {
            int gcol = nb + wc * 64 + n * 16 + l15;
#pragma unroll
            for (int r = 0; r < 4; r++) {
                int grow = mb + wr * 64 + m * 16 + lq * 4 + r;
                if (grow >= M) continue;
                float v = acc[m][n][r];
                if (EPI == 0) {
                    ((unsigned char*)Cout)[(size_t)grow * Nc + gcol] = f2fp8(v);
                } else if (EPI == 1) {
                    v += bias[gcol];
                    v = fmaxf(v, 0.f);
                    ((unsigned short*)Cout)[(size_t)grow * Nc + gcol] = f2bf(v);
                } else {
                    if (gcol < Nc) {
                        v += bias[gcol];
                        v = 1.f / (1.f + expf(-v));
                        ((float*)Cout)[(size_t)grow * Nc + gcol] = v;
                    }
                }
            }
        }
    }
}

// ------------------------------------------------------------- gate fusion

__global__ void k_gate(const unsigned short* __restrict__ h1, const unsigned short* __restrict__ h2,
                       const float* __restrict__ w1, const float* __restrict__ w1b,
                       const float* __restrict__ w2, const float* __restrict__ w2b,
                       unsigned short* __restrict__ m, int n) {
    int gtid = blockIdx.x * blockDim.x + threadIdx.x;
    int wid = gtid >> 6;
    int lane = threadIdx.x & 63;
    if (wid >= n) return;
    ushort4 av = ((const ushort4*)(h1 + (size_t)wid * HDIM))[lane];
    ushort4 bv = ((const ushort4*)(h2 + (size_t)wid * HDIM))[lane];
    float4 wa = ((const float4*)w1)[lane];
    float4 wb = ((const float4*)w2)[lane];
    float a0 = bf2f(av.x), a1 = bf2f(av.y), a2 = bf2f(av.z), a3 = bf2f(av.w);
    float b0 = bf2f(bv.x), b1 = bf2f(bv.y), b2 = bf2f(bv.z), b3 = bf2f(bv.w);
    float d1 = a0 * wa.x + a1 * wa.y + a2 * wa.z + a3 * wa.w;
    float d2 = b0 * wb.x + b1 * wb.y + b2 * wb.z + b3 * wb.w;
    for (int off = 32; off > 0; off >>= 1) {
        d1 += __shfl_xor(d1, off);
        d2 += __shfl_xor(d2, off);
    }
    float f1 = 1.f / (1.f + expf(-(d1 + w1b[0])));
    float f2 = 1.f / (1.f + expf(-(d2 + w2b[0])));
    float f = f1 / (f1 + f2);
    ushort4 o;
    o.x = f2bf(f * a0 + (1.f - f) * b0);
    o.y = f2bf(f * a1 + (1.f - f) * b1);
    o.z = f2bf(f * a2 + (1.f - f) * b2);
    o.w = f2bf(f * a3 + (1.f - f) * b3);
    ((ushort4*)(m + (size_t)wid * HDIM))[lane] = o;
}

// ------------------------------------------------------------------ launch

extern "C" void kernel_launch(void* const* d_in, const int* in_sizes, int n_in,
                              void* d_out, int out_size, void* d_ws, size_t ws_size,
                              hipStream_t stream) {
    (void)n_in; (void)out_size; (void)ws_size;
    const int N = N_NODES, E = E_EDGES;

    const float* x1; const float* x2; const int* ei1; const int* ei2;
    if (in_sizes[1] == 2 * E) {
        x1 = (const float*)d_in[0]; ei1 = (const int*)d_in[1];
        x2 = (const float*)d_in[2]; ei2 = (const int*)d_in[3];
    } else {
        x1 = (const float*)d_in[0]; x2 = (const float*)d_in[1];
        ei1 = (const int*)d_in[2]; ei2 = (const int*)d_in[3];
    }
    const float* W[2][4]; const float* Bv[2][4];
    int idx = 4;
    for (int br = 0; br < 2; br++)
        for (int l = 0; l < 4; l++) {
            W[br][l] = (const float*)d_in[idx++];
            Bv[br][l] = (const float*)d_in[idx++];
        }
    const float* w1W  = (const float*)d_in[20];
    const float* w1b  = (const float*)d_in[21];
    const float* w2W  = (const float*)d_in[22];
    const float* w2b  = (const float*)d_in[23];
    const float* finW = (const float*)d_in[24];
    const float* finb = (const float*)d_in[25];
    const float* outW = (const float*)d_in[26];
    const float* outb = (const float*)d_in[27];
    float* out = (float*)d_out;

    size_t off = 0;
    auto alloc = [&](size_t bytes) {
        void* p = (char*)d_ws + off;
        off = (off + bytes + 255) & ~(size_t)255;
        return p;
    };
    unsigned short* x1b = (unsigned short*)alloc((size_t)N * F_IN * 2);  // also fin-out t
    unsigned short* x2b = (unsigned short*)alloc((size_t)N * F_IN * 2);
    unsigned char*  g8  = (unsigned char*)alloc((size_t)N * HDIM);       // fp8 GEMM out
    unsigned short* mb_ = (unsigned short*)alloc((size_t)N * HDIM * 2);
    unsigned short* h1b = (unsigned short*)alloc((size_t)N * HDIM * 2);
    unsigned short* h2b = (unsigned short*)alloc((size_t)N * HDIM * 2);
    unsigned short* Wt[2][4];
    Wt[0][0] = (unsigned short*)alloc((size_t)HDIM * F_IN * 2);
    for (int l = 1; l < 4; l++) Wt[0][l] = (unsigned short*)alloc((size_t)HDIM * HDIM * 2);
    Wt[1][0] = (unsigned short*)alloc((size_t)HDIM * F_IN * 2);
    for (int l = 1; l < 4; l++) Wt[1][l] = (unsigned short*)alloc((size_t)HDIM * HDIM * 2);
    unsigned short* finWt = (unsigned short*)alloc((size_t)HDIM * HDIM * 2);
    unsigned short* outWt = (unsigned short*)alloc((size_t)128 * HDIM * 2);
    unsigned short* col1 = (unsigned short*)alloc((size_t)E * 2);
    unsigned short* col2 = (unsigned short*)alloc((size_t)E * 2);
    int* rank1  = (int*)alloc((size_t)E * 4);
    int* rank2  = (int*)alloc((size_t)E * 4);
    int* rp1    = (int*)alloc((size_t)(N + 1) * 4);
    int* rp2    = (int*)alloc((size_t)(N + 1) * 4);
    int* incl1  = (int*)alloc((size_t)N * 4);
    int* incl2  = (int*)alloc((size_t)N * 4);
    int* bsum1  = (int*)alloc((size_t)256 * 4);
    int* bsum2  = (int*)alloc((size_t)256 * 4);
    int* cnt1   = (int*)alloc((size_t)N * 4);
    int* cnt2   = (int*)alloc((size_t)N * 4);
    float* di1  = (float*)alloc((size_t)N * 4);
    float* di2  = (float*)alloc((size_t)N * 4);

    const int BLK = 256;
    int nwaves_grid = (N * 64 + BLK - 1) / BLK;   // 12500
    int nchunks = (N + 255) / 256;                // 196
    int mtiles = (N + 127) / 128;                 // 391
    int edge_blocks = (2 * (E >> 3) + BLK - 1) / BLK;  // 1563
    dim3 grid_h(HDIM / 128, mtiles);
    dim3 grid_o(1, mtiles);

    // fused weight conversion (10 transposes, outW zero-padded to 128 rows)
    WPack wp;
    wp.d[0] = {W[0][0], Wt[0][0], F_IN, HDIM, HDIM};
    wp.d[1] = {W[0][1], Wt[0][1], HDIM, HDIM, HDIM};
    wp.d[2] = {W[0][2], Wt[0][2], HDIM, HDIM, HDIM};
    wp.d[3] = {W[0][3], Wt[0][3], HDIM, HDIM, HDIM};
    wp.d[4] = {W[1][0], Wt[1][0], F_IN, HDIM, HDIM};
    wp.d[5] = {W[1][1], Wt[1][1], HDIM, HDIM, HDIM};
    wp.d[6] = {W[1][2], Wt[1][2], HDIM, HDIM, HDIM};
    wp.d[7] = {W[1][3], Wt[1][3], HDIM, HDIM, HDIM};
    wp.d[8] = {finW, finWt, HDIM, HDIM, HDIM};
    wp.d[9] = {outW, outWt, HDIM, L_OUT, 128};
    k_wconv<<<dim3(512, 10), BLK, 0, stream>>>(wp);

    // CSR build, both branches fused, rank trick, 8-edge batches
    hipMemsetAsync(cnt1, 0, (size_t)N * 4, stream);
    hipMemsetAsync(cnt2, 0, (size_t)N * 4, stream);
    k_rank2<<<edge_blocks, BLK, 0, stream>>>(ei1 + E, ei2 + E, cnt1, cnt2, rank1, rank2, E);
    k_scan1f<<<dim3(nchunks, 2), BLK, 0, stream>>>(cnt1, cnt2, incl1, incl2, bsum1, bsum2, N);
    k_scan2f<<<2, BLK, 0, stream>>>(bsum1, bsum2, rp1, rp2, nchunks, N);
    k_scan3f<<<dim3(nchunks, 2), BLK, 0, stream>>>(incl1, incl2, cnt1, cnt2, bsum1, bsum2, rp1, rp2, N);
    k_dinv2<<<(2 * N + BLK - 1) / BLK, BLK, 0, stream>>>(cnt1, cnt2, di1, di2, N);
    k_fill2<<<edge_blocks, BLK, 0, stream>>>(ei1, ei1 + E, ei2, ei2 + E, rank1, rank2,
                                             rp1, rp2, col1, col2, E);
    k_f2b2<<<4096, BLK, 0, stream>>>(x1, x2, x1b, x2b, N * F_IN / 4);

    // branch-sequential layers: GEMM -> agg immediately (g8 hot in L2)
    for (int br = 0; br < 2; br++) {
        const unsigned short* col = br ? col2 : col1;
        const int* rp = br ? rp2 : rp1;
        const float* di = br ? di2 : di1;
        const unsigned short* xb = br ? x2b : x1b;
        unsigned short* hb = br ? h2b : h1b;

        k_gemm<0><<<grid_h, BLK, 0, stream>>>(xb, Wt[br][0], nullptr, g8, N, F_IN, HDIM);
        k_agg<<<nwaves_grid, BLK, 0, stream>>>(g8, rp, col, di, Bv[br][0], hb, N, 1);
        for (int l = 1; l <= 2; l++) {
            k_gemm<0><<<grid_h, BLK, 0, stream>>>(hb, Wt[br][l], nullptr, g8, N, HDIM, HDIM);
            k_agg<<<nwaves_grid, BLK, 0, stream>>>(g8, rp, col, di, Bv[br][l], hb, N, 1);
        }
        k_gemm<0><<<grid_h, BLK, 0, stream>>>(hb, Wt[br][3], nullptr, g8, N, HDIM, HDIM);
        k_agg<<<nwaves_grid, BLK, 0, stream>>>(g8, rp, col, di, Bv[br][3], hb, N, 0);
    }

    k_gate<<<nwaves_grid, BLK, 0, stream>>>(h1b, h2b, w1W, w1b, w2W, w2b, mb_, N);
    k_gemm<1><<<grid_h, BLK, 0, stream>>>(mb_, finWt, finb, x1b, N, HDIM, HDIM);
    k_gemm<2><<<grid_o, BLK, 0, stream>>>(x1b, outWt, outb, out, N, HDIM, L_OUT);
}

// Round 11
// 992.615 us; speedup vs baseline: 2.1602x; 1.0004x over previous
//
#include <hip/hip_runtime.h>
#include <math.h>

#define N_NODES 50000
#define F_IN    512
#define HDIM    256
#define L_OUT   52
#define E_EDGES 1600000

typedef short short8 __attribute__((ext_vector_type(8)));
typedef unsigned short u16x8 __attribute__((ext_vector_type(8)));
typedef float f32x4 __attribute__((ext_vector_type(4)));
typedef float f32x2 __attribute__((ext_vector_type(2)));

__device__ __forceinline__ float bf2f(unsigned short u) {
    unsigned int x = ((unsigned int)u) << 16;
    return __builtin_bit_cast(float, x);
}
__device__ __forceinline__ unsigned short f2bf(float f) {
    unsigned int u = __builtin_bit_cast(unsigned int, f);
    return (unsigned short)((u + 0x7fffu + ((u >> 16) & 1u)) >> 16);
}
__device__ __forceinline__ unsigned char f2fp8(float f) {
    int pk = __builtin_amdgcn_cvt_pk_fp8_f32(f, 0.f, 0, false);
    return (unsigned char)(pk & 0xff);
}
__device__ __forceinline__ void gload16(const unsigned short* g, unsigned short* l) {
    __builtin_amdgcn_global_load_lds(
        (const __attribute__((address_space(1))) unsigned int*)(g),
        (__attribute__((address_space(3))) unsigned int*)(l), 16, 0, 0);
}

struct WDesc { const float* in; unsigned short* out; int K; int N; int Npad; int nblk; };
struct WPack { WDesc d[10]; };

// ---------------- packed prologue: rank atomics || x f2b || weight transpose
// independent work in one dispatch so the BW-bound parts hide the atomic wall

__global__ __launch_bounds__(256) void k_init(
    const int* __restrict__ d1, const int* __restrict__ d2,
    int* __restrict__ c1, int* __restrict__ c2,
    int* __restrict__ rk1, int* __restrict__ rk2, int E,
    const float* __restrict__ x1, const float* __restrict__ x2,
    unsigned short* __restrict__ o1, unsigned short* __restrict__ o2, int n4,
    WPack wp, int nRank, int nF2b) {
    int b = blockIdx.x;
    if (b < nRank) {
        // ---- rank section: 8 edges/thread, returning atomics
        int tid = b * 256 + threadIdx.x;
        int half = E >> 3;
        if (tid >= 2 * half) return;
        int br = tid >= half;
        const int* D = br ? d2 : d1;
        int* C = br ? c2 : c1;
        int* RK = br ? rk2 : rk1;
        int e = (br ? tid - half : tid) << 3;
        int4 da = ((const int4*)(D + e))[0];
        int4 db = ((const int4*)(D + e))[1];
        int r0 = atomicAdd(&C[da.x], 1);
        int r1 = atomicAdd(&C[da.y], 1);
        int r2 = atomicAdd(&C[da.z], 1);
        int r3 = atomicAdd(&C[da.w], 1);
        int r4 = atomicAdd(&C[db.x], 1);
        int r5 = atomicAdd(&C[db.y], 1);
        int r6 = atomicAdd(&C[db.z], 1);
        int r7 = atomicAdd(&C[db.w], 1);
        ((int4*)(RK + e))[0] = make_int4(r0, r1, r2, r3);
        ((int4*)(RK + e))[1] = make_int4(r4, r5, r6, r7);
    } else if (b < nRank + nF2b) {
        // ---- f2b section: grid-stride over both x tensors
        int i = (b - nRank) * 256 + threadIdx.x;
        int stride = nF2b * 256;
        int tot = 2 * n4;
        for (; i < tot; i += stride) {
            int br = i >= n4;
            int e = br ? i - n4 : i;
            float4 v = ((const float4*)(br ? x2 : x1))[e];
            ushort4 o;
            o.x = f2bf(v.x); o.y = f2bf(v.y); o.z = f2bf(v.z); o.w = f2bf(v.w);
            ((ushort4*)(br ? o2 : o1))[e] = o;
        }
    } else {
        // ---- wconv section: fp32 [K][N] -> bf16 [Npad][K], zero-padded
        int wb = b - nRank - nF2b;
        for (int ii = 0; ii < 10; ii++) {
            WDesc w = wp.d[ii];
            if (wb < w.nblk) {
                int idx = wb * 256 + threadIdx.x;
                if (idx < w.K * w.Npad) {
                    int nn = idx / w.K, kk = idx - nn * w.K;
                    w.out[idx] = (nn < w.N) ? f2bf(w.in[(size_t)kk * w.N + nn])
                                            : (unsigned short)0;
                }
                return;
            }
            wb -= w.nblk;
        }
    }
}

// --------------------------------------------------------- scans (per branch)

__global__ void k_dinv2(const int* __restrict__ c1, const int* __restrict__ c2,
                        float* __restrict__ v1, float* __restrict__ v2, int n) {
    int i = blockIdx.x * blockDim.x + threadIdx.x;
    if (i < n) v1[i] = rsqrtf((float)(c1[i] + 1));
    else if (i < 2 * n) v2[i - n] = rsqrtf((float)(c2[i - n] + 1));
}

__global__ void k_scan1f(const int* __restrict__ c1, const int* __restrict__ c2,
                         int* __restrict__ i1, int* __restrict__ i2,
                         int* __restrict__ b1, int* __restrict__ b2, int n) {
    const int* cnt = blockIdx.y ? c2 : c1;
    int* incl = blockIdx.y ? i2 : i1;
    int* bsum = blockIdx.y ? b2 : b1;
    __shared__ int s[256];
    int tid = threadIdx.x;
    int idx = blockIdx.x * 256 + tid;
    int v = (idx < n) ? cnt[idx] : 0;
    s[tid] = v;
    __syncthreads();
#pragma unroll
    for (int off = 1; off < 256; off <<= 1) {
        int t = (tid >= off) ? s[tid - off] : 0;
        __syncthreads();
        s[tid] += t;
        __syncthreads();
    }
    if (idx < n) incl[idx] = s[tid];
    if (tid == 255) bsum[blockIdx.x] = s[255];
}

__global__ void k_scan2f(int* __restrict__ b1, int* __restrict__ b2,
                         int* __restrict__ r1, int* __restrict__ r2, int nb, int n) {
    int* bsum = blockIdx.x ? b2 : b1;
    int* rowptr = blockIdx.x ? r2 : r1;
    __shared__ int s[256];
    int tid = threadIdx.x;
    int v = (tid < nb) ? bsum[tid] : 0;
    s[tid] = v;
    __syncthreads();
#pragma unroll
    for (int off = 1; off < 256; off <<= 1) {
        int t = (tid >= off) ? s[tid - off] : 0;
        __syncthreads();
        s[tid] += t;
        __syncthreads();
    }
    if (tid < nb) bsum[tid] = s[tid] - v;
    if (tid == nb - 1) rowptr[n] = s[tid];
}

__global__ void k_scan3f(const int* __restrict__ i1, const int* __restrict__ i2,
                         const int* __restrict__ c1, const int* __restrict__ c2,
                         const int* __restrict__ b1, const int* __restrict__ b2,
                         int* __restrict__ r1, int* __restrict__ r2, int n) {
    const int* incl = blockIdx.y ? i2 : i1;
    const int* cnt  = blockIdx.y ? c2 : c1;
    const int* bsum = blockIdx.y ? b2 : b1;
    int* rowptr     = blockIdx.y ? r2 : r1;
    int i = blockIdx.x * blockDim.x + threadIdx.x;
    if (i < n) rowptr[i] = incl[i] - cnt[i] + bsum[i >> 8];
}

// atomic-free fill, 8-edge batch: record = {u16 col | bf16 weight}
__global__ void k_fill2(const int* __restrict__ s1, const int* __restrict__ d1,
                        const int* __restrict__ s2, const int* __restrict__ d2,
                        const int* __restrict__ rk1, const int* __restrict__ rk2,
                        const int* __restrict__ rp1, const int* __restrict__ rp2,
                        const float* __restrict__ v1, const float* __restrict__ v2,
                        unsigned int* __restrict__ cw1, unsigned int* __restrict__ cw2,
                        int E) {
    int tid = blockIdx.x * blockDim.x + threadIdx.x;
    int half = E >> 3;
    if (tid >= 2 * half) return;
    int br = tid >= half;
    const int* S = br ? s2 : s1;
    const int* D = br ? d2 : d1;
    const int* RK = br ? rk2 : rk1;
    const int* RP = br ? rp2 : rp1;
    const float* V = br ? v2 : v1;
    unsigned int* C = br ? cw2 : cw1;
    int e = (br ? tid - half : tid) << 3;
    int4 da = ((const int4*)(D + e))[0];
    int4 db = ((const int4*)(D + e))[1];
    int4 sa = ((const int4*)(S + e))[0];
    int4 sb = ((const int4*)(S + e))[1];
    int4 ra = ((const int4*)(RK + e))[0];
    int4 rb = ((const int4*)(RK + e))[1];
    int dd[8] = {da.x, da.y, da.z, da.w, db.x, db.y, db.z, db.w};
    int ss[8] = {sa.x, sa.y, sa.z, sa.w, sb.x, sb.y, sb.z, sb.w};
    int rr[8] = {ra.x, ra.y, ra.z, ra.w, rb.x, rb.y, rb.z, rb.w};
#pragma unroll
    for (int t = 0; t < 8; t++) {
        float w = V[ss[t]] * V[dd[t]];
        C[RP[dd[t]] + rr[t]] =
            (unsigned int)(unsigned short)ss[t] | ((unsigned int)f2bf(w) << 16);
    }
}

// ------- aggregation: wave/node, lane-halves = even/odd streams, 16-deep
//         (32 rows in flight), weight baked into the 4B edge record.

__global__ void k_agg(const unsigned char* __restrict__ g, const int* __restrict__ rowptr,
                      const unsigned int* __restrict__ cw,
                      const float* __restrict__ dinv,
                      const float* __restrict__ bias, unsigned short* __restrict__ out,
                      int n, int do_relu) {
    int gtid = blockIdx.x * blockDim.x + threadIdx.x;
    int wid = gtid >> 6;
    if (wid >= n) return;
    int lane = threadIdx.x & 63;
    int half = lane >> 5;   // even/odd neighbor stream
    int fl = lane & 31;     // 8B slice of the 256B fp8 row

    float a[8];
#pragma unroll
    for (int k = 0; k < 8; k++) a[k] = 0.f;

    int r0 = rowptr[wid], r1 = rowptr[wid + 1];
    int base = r0;

    for (; base + 32 <= r1; base += 32) {
        unsigned int c[16]; uint2 v[16];
#pragma unroll
        for (int t = 0; t < 16; t++) c[t] = cw[base + 2 * t + half];
#pragma unroll
        for (int t = 0; t < 16; t++)
            v[t] = ((const uint2*)(g + (size_t)(c[t] & 0xffffu) * HDIM))[fl];
#pragma unroll
        for (int t = 0; t < 16; t++) {
            float w = bf2f((unsigned short)(c[t] >> 16));
            f32x2 p0 = __builtin_amdgcn_cvt_pk_f32_fp8((int)v[t].x, false);
            f32x2 p1 = __builtin_amdgcn_cvt_pk_f32_fp8((int)v[t].x, true);
            f32x2 p2 = __builtin_amdgcn_cvt_pk_f32_fp8((int)v[t].y, false);
            f32x2 p3 = __builtin_amdgcn_cvt_pk_f32_fp8((int)v[t].y, true);
            a[0] = fmaf(p0[0], w, a[0]); a[1] = fmaf(p0[1], w, a[1]);
            a[2] = fmaf(p1[0], w, a[2]); a[3] = fmaf(p1[1], w, a[3]);
            a[4] = fmaf(p2[0], w, a[4]); a[5] = fmaf(p2[1], w, a[5]);
            a[6] = fmaf(p3[0], w, a[6]); a[7] = fmaf(p3[1], w, a[7]);
        }
    }
    for (; base + 16 <= r1; base += 16) {
        unsigned int c[8]; uint2 v[8];
#pragma unroll
        for (int t = 0; t < 8; t++) c[t] = cw[base + 2 * t + half];
#pragma unroll
        for (int t = 0; t < 8; t++)
            v[t] = ((const uint2*)(g + (size_t)(c[t] & 0xffffu) * HDIM))[fl];
#pragma unroll
        for (int t = 0; t < 8; t++) {
            float w = bf2f((unsigned short)(c[t] >> 16));
            f32x2 p0 = __builtin_amdgcn_cvt_pk_f32_fp8((int)v[t].x, false);
            f32x2 p1 = __builtin_amdgcn_cvt_pk_f32_fp8((int)v[t].x, true);
            f32x2 p2 = __builtin_amdgcn_cvt_pk_f32_fp8((int)v[t].y, false);
            f32x2 p3 = __builtin_amdgcn_cvt_pk_f32_fp8((int)v[t].y, true);
            a[0] = fmaf(p0[0], w, a[0]); a[1] = fmaf(p0[1], w, a[1]);
            a[2] = fmaf(p1[0], w, a[2]); a[3] = fmaf(p1[1], w, a[3]);
            a[4] = fmaf(p2[0], w, a[4]); a[5] = fmaf(p2[1], w, a[5]);
            a[6] = fmaf(p3[0], w, a[6]); a[7] = fmaf(p3[1], w, a[7]);
        }
    }
    if (base < r1) {  // remainder 1..15, zero-weight padding
        unsigned int c[8]; uint2 v[8]; float w[8];
#pragma unroll
        for (int t = 0; t < 8; t++) {
            int idx = base + 2 * t + half;
            int ok = idx < r1;
            c[t] = cw[ok ? idx : r0];
            w[t] = ok ? bf2f((unsigned short)(c[t] >> 16)) : 0.f;
        }
#pragma unroll
        for (int t = 0; t < 8; t++)
            v[t] = ((const uint2*)(g + (size_t)(c[t] & 0xffffu) * HDIM))[fl];
#pragma unroll
        for (int t = 0; t < 8; t++) {
            f32x2 p0 = __builtin_amdgcn_cvt_pk_f32_fp8((int)v[t].x, false);
            f32x2 p1 = __builtin_amdgcn_cvt_pk_f32_fp8((int)v[t].x, true);
            f32x2 p2 = __builtin_amdgcn_cvt_pk_f32_fp8((int)v[t].y, false);
            f32x2 p3 = __builtin_amdgcn_cvt_pk_f32_fp8((int)v[t].y, true);
            a[0] = fmaf(p0[0], w[t], a[0]); a[1] = fmaf(p0[1], w[t], a[1]);
            a[2] = fmaf(p1[0], w[t], a[2]); a[3] = fmaf(p1[1], w[t], a[3]);
            a[4] = fmaf(p2[0], w[t], a[4]); a[5] = fmaf(p2[1], w[t], a[5]);
            a[6] = fmaf(p3[0], w[t], a[6]); a[7] = fmaf(p3[1], w[t], a[7]);
        }
    }

    // combine even/odd partial sums
#pragma unroll
    for (int k = 0; k < 8; k++) a[k] += __shfl_xor(a[k], 32);

    // self-loop + bias + activation (redundant on both halves, store once)
    float di = dinv[wid];
    float w0 = di * di;
    uint2 sv = ((const uint2*)(g + (size_t)wid * HDIM))[fl];
    f32x2 s0 = __builtin_amdgcn_cvt_pk_f32_fp8((int)sv.x, false);
    f32x2 s1 = __builtin_amdgcn_cvt_pk_f32_fp8((int)sv.x, true);
    f32x2 s2 = __builtin_amdgcn_cvt_pk_f32_fp8((int)sv.y, false);
    f32x2 s3 = __builtin_amdgcn_cvt_pk_f32_fp8((int)sv.y, true);
    float sf[8] = {s0[0], s0[1], s1[0], s1[1], s2[0], s2[1], s3[0], s3[1]};
    u16x8 o;
#pragma unroll
    for (int k = 0; k < 8; k++) {
        float x = fmaf(sf[k], w0, a[k]) + bias[fl * 8 + k];
        if (do_relu) x = fmaxf(x, 0.f);
        o[k] = f2bf(x);
    }
    if (half == 0)
        ((u16x8*)(out + (size_t)wid * HDIM))[fl] = o;
}

// --------------------------------------------------- bf16 MFMA GEMM 128x128
// EPI 0: raw -> fp8 C.  EPI 1: bias+relu -> bf16.  EPI 2: bias+sigmoid -> fp32.

template <int EPI>
__global__ __launch_bounds__(256) void k_gemm(const unsigned short* __restrict__ A,
                                              const unsigned short* __restrict__ Bt,
                                              const float* __restrict__ bias,
                                              void* __restrict__ Cout,
                                              int M, int K, int Nc) {
    __shared__ __align__(16) unsigned short As[128 * 32];
    __shared__ __align__(16) unsigned short Bs[128 * 32];
    int tid = threadIdx.x;
    int wid = tid >> 6, lane = tid & 63;
    int wr = wid >> 1, wc = wid & 1;
    int mb = blockIdx.y * 128, nb = blockIdx.x * 128;

    int sr = tid >> 2;
    int ssl = (tid & 3) ^ ((sr >> 1) & 3);
    int ar0 = mb + sr;      if (ar0 > M - 1) ar0 = M - 1;
    int ar1 = mb + sr + 64; if (ar1 > M - 1) ar1 = M - 1;
    const unsigned short* gA0 = A + (size_t)ar0 * K + ssl * 8;
    const unsigned short* gA1 = A + (size_t)ar1 * K + ssl * 8;
    const unsigned short* gB0 = Bt + (size_t)(nb + sr) * K + ssl * 8;
    const unsigned short* gB1 = Bt + (size_t)(nb + sr + 64) * K + ssl * 8;
    unsigned short* ldsA = As + tid * 8;
    unsigned short* ldsB = Bs + tid * 8;

    f32x4 acc[4][4];
#pragma unroll
    for (int m = 0; m < 4; m++)
#pragma unroll
        for (int n = 0; n < 4; n++) acc[m][n] = (f32x4){0.f, 0.f, 0.f, 0.f};

    int l15 = lane & 15, ks = lane >> 4;

    for (int k0 = 0; k0 < K; k0 += 32) {
        gload16(gA0 + k0, ldsA);
        gload16(gA1 + k0, ldsA + 2048);
        gload16(gB0 + k0, ldsB);
        gload16(gB1 + k0, ldsB + 2048);
        __syncthreads();

        short8 af[4], bfr[4];
#pragma unroll
        for (int m = 0; m < 4; m++) {
            int row = wr * 64 + m * 16 + l15;
            int slot = ks ^ ((row >> 1) & 3);
            af[m] = *(const short8*)((const char*)As + row * 64 + slot * 16);
        }
#pragma unroll
        for (int n = 0; n < 4; n++) {
            int row = wc * 64 + n * 16 + l15;
            int slot = ks ^ ((row >> 1) & 3);
            bfr[n] = *(const short8*)((const char*)Bs + row * 64 + slot * 16);
        }
#pragma unroll
        for (int m = 0; m < 4; m++)
#pragma unroll
            for (int n = 0; n < 4; n++)
                acc[m][n] = __builtin_amdgcn_mfma_f32_16x16x32_bf16(af[m], bfr[n], acc[m][n], 0, 0, 0);
        __syncthreads();
    }

    int lq = lane >> 4;
#pragma unroll
    for (int m = 0; m < 4; m++) {
#pragma unroll
        for (int n = 0; n < 4; n++) {
            int gcol = nb + wc * 64 + n * 16 + l15;
#pragma unroll
            for (int r = 0; r < 4; r++) {
                int grow = mb + wr * 64 + m * 16 + lq * 4 + r;
                if (grow >= M) continue;
                float v = acc[m][n][r];
                if (EPI == 0) {
                    ((unsigned char*)Cout)[(size_t)grow * Nc + gcol] = f2fp8(v);
                } else if (EPI == 1) {
                    v += bias[gcol];
                    v = fmaxf(v, 0.f);
                    ((unsigned short*)Cout)[(size_t)grow * Nc + gcol] = f2bf(v);
                } else {
                    if (gcol < Nc) {
                        v += bias[gcol];
                        v = 1.f / (1.f + expf(-v));
                        ((float*)Cout)[(size_t)grow * Nc + gcol] = v;
                    }
                }
            }
        }
    }
}

// ------------------------------------------------------------- gate fusion

__global__ void k_gate(const unsigned short* __restrict__ h1, const unsigned short* __restrict__ h2,
                       const float* __restrict__ w1, const float* __restrict__ w1b,
                       const float* __restrict__ w2, const float* __restrict__ w2b,
                       unsigned short* __restrict__ m, int n) {
    int gtid = blockIdx.x * blockDim.x + threadIdx.x;
    int wid = gtid >> 6;
    int lane = threadIdx.x & 63;
    if (wid >= n) return;
    ushort4 av = ((const ushort4*)(h1 + (size_t)wid * HDIM))[lane];
    ushort4 bv = ((const ushort4*)(h2 + (size_t)wid * HDIM))[lane];
    float4 wa = ((const float4*)w1)[lane];
    float4 wb = ((const float4*)w2)[lane];
    float a0 = bf2f(av.x), a1 = bf2f(av.y), a2 = bf2f(av.z), a3 = bf2f(av.w);
    float b0 = bf2f(bv.x), b1 = bf2f(bv.y), b2 = bf2f(bv.z), b3 = bf2f(bv.w);
    float d1 = a0 * wa.x + a1 * wa.y + a2 * wa.z + a3 * wa.w;
    float d2 = b0 * wb.x + b1 * wb.y + b2 * wb.z + b3 * wb.w;
    for (int off = 32; off > 0; off >>= 1) {
        d1 += __shfl_xor(d1, off);
        d2 += __shfl_xor(d2, off);
    }
    float f1 = 1.f / (1.f + expf(-(d1 + w1b[0])));
    float f2 = 1.f / (1.f + expf(-(d2 + w2b[0])));
    float f = f1 / (f1 + f2);
    ushort4 o;
    o.x = f2bf(f * a0 + (1.f - f) * b0);
    o.y = f2bf(f * a1 + (1.f - f) * b1);
    o.z = f2bf(f * a2 + (1.f - f) * b2);
    o.w = f2bf(f * a3 + (1.f - f) * b3);
    ((ushort4*)(m + (size_t)wid * HDIM))[lane] = o;
}

// ------------------------------------------------------------------ launch

extern "C" void kernel_launch(void* const* d_in, const int* in_sizes, int n_in,
                              void* d_out, int out_size, void* d_ws, size_t ws_size,
                              hipStream_t stream) {
    (void)n_in; (void)out_size; (void)ws_size;
    const int N = N_NODES, E = E_EDGES;

    const float* x1; const float* x2; const int* ei1; const int* ei2;
    if (in_sizes[1] == 2 * E) {
        x1 = (const float*)d_in[0]; ei1 = (const int*)d_in[1];
        x2 = (const float*)d_in[2]; ei2 = (const int*)d_in[3];
    } else {
        x1 = (const float*)d_in[0]; x2 = (const float*)d_in[1];
        ei1 = (const int*)d_in[2]; ei2 = (const int*)d_in[3];
    }
    const float* W[2][4]; const float* Bv[2][4];
    int idx = 4;
    for (int br = 0; br < 2; br++)
        for (int l = 0; l < 4; l++) {
            W[br][l] = (const float*)d_in[idx++];
            Bv[br][l] = (const float*)d_in[idx++];
        }
    const float* w1W  = (const float*)d_in[20];
    const float* w1b  = (const float*)d_in[21];
    const float* w2W  = (const float*)d_in[22];
    const float* w2b  = (const float*)d_in[23];
    const float* finW = (const float*)d_in[24];
    const float* finb = (const float*)d_in[25];
    const float* outW = (const float*)d_in[26];
    const float* outb = (const float*)d_in[27];
    float* out = (float*)d_out;

    size_t off = 0;
    auto alloc = [&](size_t bytes) {
        void* p = (char*)d_ws + off;
        off = (off + bytes + 255) & ~(size_t)255;
        return p;
    };
    unsigned short* x1b = (unsigned short*)alloc((size_t)N * F_IN * 2);  // also fin-out t
    unsigned short* x2b = (unsigned short*)alloc((size_t)N * F_IN * 2);
    unsigned char*  g8  = (unsigned char*)alloc((size_t)N * HDIM);       // fp8 GEMM out
    unsigned short* mb_ = (unsigned short*)alloc((size_t)N * HDIM * 2);
    unsigned short* h1b = (unsigned short*)alloc((size_t)N * HDIM * 2);
    unsigned short* h2b = (unsigned short*)alloc((size_t)N * HDIM * 2);
    unsigned short* Wt[2][4];
    Wt[0][0] = (unsigned short*)alloc((size_t)HDIM * F_IN * 2);
    for (int l = 1; l < 4; l++) Wt[0][l] = (unsigned short*)alloc((size_t)HDIM * HDIM * 2);
    Wt[1][0] = (unsigned short*)alloc((size_t)HDIM * F_IN * 2);
    for (int l = 1; l < 4; l++) Wt[1][l] = (unsigned short*)alloc((size_t)HDIM * HDIM * 2);
    unsigned short* finWt = (unsigned short*)alloc((size_t)HDIM * HDIM * 2);
    unsigned short* outWt = (unsigned short*)alloc((size_t)128 * HDIM * 2);
    unsigned int* cw1 = (unsigned int*)alloc((size_t)E * 4);
    unsigned int* cw2 = (unsigned int*)alloc((size_t)E * 4);
    int* rank1  = (int*)alloc((size_t)E * 4);
    int* rank2  = (int*)alloc((size_t)E * 4);
    int* rp1    = (int*)alloc((size_t)(N + 1) * 4);
    int* rp2    = (int*)alloc((size_t)(N + 1) * 4);
    int* incl1  = (int*)alloc((size_t)N * 4);
    int* incl2  = (int*)alloc((size_t)N * 4);
    int* bsum1  = (int*)alloc((size_t)256 * 4);
    int* bsum2  = (int*)alloc((size_t)256 * 4);
    int* cnt1   = (int*)alloc((size_t)N * 4);
    int* cnt2   = (int*)alloc((size_t)N * 4);
    float* di1  = (float*)alloc((size_t)N * 4);
    float* di2  = (float*)alloc((size_t)N * 4);

    const int BLK = 256;
    int nwaves_grid = (N * 64 + BLK - 1) / BLK;   // 12500
    int nchunks = (N + 255) / 256;                // 196
    int mtiles = (N + 127) / 128;                 // 391
    int edge_blocks = (2 * (E >> 3) + BLK - 1) / BLK;  // 1563
    dim3 grid_h(HDIM / 128, mtiles);
    dim3 grid_o(1, mtiles);

    // packed prologue descriptors
    WPack wp;
    wp.d[0] = {W[0][0], Wt[0][0], F_IN, HDIM, HDIM, 0};
    wp.d[1] = {W[0][1], Wt[0][1], HDIM, HDIM, HDIM, 0};
    wp.d[2] = {W[0][2], Wt[0][2], HDIM, HDIM, HDIM, 0};
    wp.d[3] = {W[0][3], Wt[0][3], HDIM, HDIM, HDIM, 0};
    wp.d[4] = {W[1][0], Wt[1][0], F_IN, HDIM, HDIM, 0};
    wp.d[5] = {W[1][1], Wt[1][1], HDIM, HDIM, HDIM, 0};
    wp.d[6] = {W[1][2], Wt[1][2], HDIM, HDIM, HDIM, 0};
    wp.d[7] = {W[1][3], Wt[1][3], HDIM, HDIM, HDIM, 0};
    wp.d[8] = {finW, finWt, HDIM, HDIM, HDIM, 0};
    wp.d[9] = {outW, outWt, HDIM, L_OUT, 128, 0};
    int nW = 0;
    for (int i = 0; i < 10; i++) {
        wp.d[i].nblk = (wp.d[i].K * wp.d[i].Npad + 255) / 256;
        nW += wp.d[i].nblk;
    }
    int nRank = edge_blocks;  // 1563
    int nF2b = 4096;

    hipMemsetAsync(cnt1, 0, (size_t)N * 4, stream);
    hipMemsetAsync(cnt2, 0, (size_t)N * 4, stream);
    k_init<<<nRank + nF2b + nW, BLK, 0, stream>>>(
        ei1 + E, ei2 + E, cnt1, cnt2, rank1, rank2, E,
        x1, x2, x1b, x2b, N * F_IN / 4, wp, nRank, nF2b);
    k_scan1f<<<dim3(nchunks, 2), BLK, 0, stream>>>(cnt1, cnt2, incl1, incl2, bsum1, bsum2, N);
    k_scan2f<<<2, BLK, 0, stream>>>(bsum1, bsum2, rp1, rp2, nchunks, N);
    k_scan3f<<<dim3(nchunks, 2), BLK, 0, stream>>>(incl1, incl2, cnt1, cnt2, bsum1, bsum2, rp1, rp2, N);
    k_dinv2<<<(2 * N + BLK - 1) / BLK, BLK, 0, stream>>>(cnt1, cnt2, di1, di2, N);
    k_fill2<<<edge_blocks, BLK, 0, stream>>>(ei1, ei1 + E, ei2, ei2 + E, rank1, rank2,
                                             rp1, rp2, di1, di2, cw1, cw2, E);

    // branch-sequential layers: GEMM -> agg immediately (g8 hot in L2)
    for (int br = 0; br < 2; br++) {
        const unsigned int* cw = br ? cw2 : cw1;
        const int* rp = br ? rp2 : rp1;
        const float* di = br ? di2 : di1;
        const unsigned short* xb = br ? x2b : x1b;
        unsigned short* hb = br ? h2b : h1b;

        k_gemm<0><<<grid_h, BLK, 0, stream>>>(xb, Wt[br][0], nullptr, g8, N, F_IN, HDIM);
        k_agg<<<nwaves_grid, BLK, 0, stream>>>(g8, rp, cw, di, Bv[br][0], hb, N, 1);
        for (int l = 1; l <= 2; l++) {
            k_gemm<0><<<grid_h, BLK, 0, stream>>>(hb, Wt[br][l], nullptr, g8, N, HDIM, HDIM);
            k_agg<<<nwaves_grid, BLK, 0, stream>>>(g8, rp, cw, di, Bv[br][l], hb, N, 1);
        }
        k_gemm<0><<<grid_h, BLK, 0, stream>>>(hb, Wt[br][3], nullptr, g8, N, HDIM, HDIM);
        k_agg<<<nwaves_grid, BLK, 0, stream>>>(g8, rp, cw, di, Bv[br][3], hb, N, 0);
    }

    k_gate<<<nwaves_grid, BLK, 0, stream>>>(h1b, h2b, w1W, w1b, w2W, w2b, mb_, N);
    k_gemm<1><<<grid_h, BLK, 0, stream>>>(mb_, finWt, finb, x1b, N, HDIM, HDIM);
    k_gemm<2><<<grid_o, BLK, 0, stream>>>(x1b, outWt, outb, out, N, HDIM, L_OUT);
}

// Round 12
// 892.632 us; speedup vs baseline: 2.4022x; 1.1120x over previous
//
#include <hip/hip_runtime.h>
#include <math.h>

#define N_NODES 50000
#define F_IN    512
#define HDIM    256
#define L_OUT   52
#define E_EDGES 1600000
#define NB1     391      // ceil(N/128) level-1 buckets (dst>>7)
#define EB      2048     // edges per chunk
#define NBLK    782      // ceil(E/EB)

typedef short short8 __attribute__((ext_vector_type(8)));
typedef unsigned short u16x8 __attribute__((ext_vector_type(8)));
typedef float f32x4 __attribute__((ext_vector_type(4)));
typedef float f32x2 __attribute__((ext_vector_type(2)));

__device__ __forceinline__ float bf2f(unsigned short u) {
    unsigned int x = ((unsigned int)u) << 16;
    return __builtin_bit_cast(float, x);
}
__device__ __forceinline__ unsigned short f2bf(float f) {
    unsigned int u = __builtin_bit_cast(unsigned int, f);
    return (unsigned short)((u + 0x7fffu + ((u >> 16) & 1u)) >> 16);
}
__device__ __forceinline__ unsigned char f2fp8(float f) {
    int pk = __builtin_amdgcn_cvt_pk_fp8_f32(f, 0.f, 0, false);
    return (unsigned char)(pk & 0xff);
}
__device__ __forceinline__ void gload16(const unsigned short* g, unsigned short* l) {
    __builtin_amdgcn_global_load_lds(
        (const __attribute__((address_space(1))) unsigned int*)(g),
        (__attribute__((address_space(3))) unsigned int*)(l), 16, 0, 0);
}

// ---------------- CSR build: atomic-free two-level counting sort ----------

// P1: per-chunk LDS histogram of bucket = dst>>7
__global__ __launch_bounds__(256) void k_hist(const int* __restrict__ d1, const int* __restrict__ d2,
                                              int* __restrict__ h1, int* __restrict__ h2, int E) {
    const int* D = blockIdx.y ? d2 : d1;
    int* H = blockIdx.y ? h2 : h1;
    __shared__ int h[NB1];
    for (int t = threadIdx.x; t < NB1; t += 256) h[t] = 0;
    __syncthreads();
    int base = blockIdx.x * EB;
#pragma unroll
    for (int k = 0; k < 8; k++) {
        int e = base + k * 256 + threadIdx.x;
        if (e < E) atomicAdd(&h[D[e] >> 7], 1);   // LDS atomic
    }
    __syncthreads();
    for (int t = threadIdx.x; t < NB1; t += 256)
        H[(size_t)t * NBLK + blockIdx.x] = h[t];
}

// P2a: per-bucket exclusive scan over chunks (in place), emit bucket totals
__global__ __launch_bounds__(256) void k_scanb(int* __restrict__ h1, int* __restrict__ h2,
                                               int* __restrict__ t1, int* __restrict__ t2) {
    int* H = blockIdx.y ? h2 : h1;
    int* T = blockIdx.y ? t2 : t1;
    int b = blockIdx.x;
    __shared__ int s[256];
    int carry = 0;
    for (int base = 0; base < NBLK; base += 256) {
        int i = base + threadIdx.x;
        int v = (i < NBLK) ? H[(size_t)b * NBLK + i] : 0;
        s[threadIdx.x] = v;
        __syncthreads();
        for (int off = 1; off < 256; off <<= 1) {
            int t = (threadIdx.x >= off) ? s[threadIdx.x - off] : 0;
            __syncthreads();
            s[threadIdx.x] += t;
            __syncthreads();
        }
        if (i < NBLK) H[(size_t)b * NBLK + i] = carry + s[threadIdx.x] - v;
        int ct = s[255];
        __syncthreads();
        carry += ct;
    }
    if (threadIdx.x == 0) T[b] = carry;
}

// P2b: exclusive scan of bucket totals -> bstart (512 threads, NB1=391)
__global__ __launch_bounds__(512) void k_bstart(const int* __restrict__ t1, const int* __restrict__ t2,
                                                int* __restrict__ b1, int* __restrict__ b2,
                                                int* __restrict__ rp1, int* __restrict__ rp2,
                                                int N, int E) {
    const int* T = blockIdx.y ? t2 : t1;
    int* BS = blockIdx.y ? b2 : b1;
    int* RP = blockIdx.y ? rp2 : rp1;
    __shared__ int s[512];
    int v = (threadIdx.x < NB1) ? T[threadIdx.x] : 0;
    s[threadIdx.x] = v;
    __syncthreads();
    for (int off = 1; off < 512; off <<= 1) {
        int t = (threadIdx.x >= off) ? s[threadIdx.x - off] : 0;
        __syncthreads();
        s[threadIdx.x] += t;
        __syncthreads();
    }
    if (threadIdx.x < NB1) BS[threadIdx.x] = s[threadIdx.x] - v;
    if (threadIdx.x == 0) { BS[NB1] = E; RP[N] = E; }
}

// P3: scatter edges into bucket-ordered record array {src | dst<<16}
__global__ __launch_bounds__(256) void k_scatter(const int* __restrict__ s1, const int* __restrict__ d1,
                                                 const int* __restrict__ s2, const int* __restrict__ d2,
                                                 const int* __restrict__ h1, const int* __restrict__ h2,
                                                 const int* __restrict__ b1, const int* __restrict__ b2,
                                                 unsigned int* __restrict__ r1, unsigned int* __restrict__ r2,
                                                 int E) {
    int br = blockIdx.y;
    const int* S = br ? s2 : s1;
    const int* D = br ? d2 : d1;
    const int* H = br ? h2 : h1;
    const int* BS = br ? b2 : b1;
    unsigned int* R = br ? r2 : r1;
    __shared__ int cur[NB1];
    for (int t = threadIdx.x; t < NB1; t += 256)
        cur[t] = BS[t] + H[(size_t)t * NBLK + blockIdx.x];
    __syncthreads();
    int base = blockIdx.x * EB;
#pragma unroll
    for (int k = 0; k < 8; k++) {
        int e = base + k * 256 + threadIdx.x;
        if (e < E) {
            int d = D[e];
            int p = atomicAdd(&cur[d >> 7], 1);   // LDS atomic, block-exclusive range
            R[p] = (unsigned int)(S[e] & 0xFFFF) | ((unsigned int)d << 16);
        }
    }
}

// P4: per-bucket 128-slot counting sort -> cnt, rowptr, u16 col
__global__ __launch_bounds__(256) void k_sort(const unsigned int* __restrict__ r1,
                                              const unsigned int* __restrict__ r2,
                                              const int* __restrict__ b1, const int* __restrict__ b2,
                                              int* __restrict__ c1, int* __restrict__ c2,
                                              int* __restrict__ rp1, int* __restrict__ rp2,
                                              unsigned short* __restrict__ col1,
                                              unsigned short* __restrict__ col2, int N) {
    int br = blockIdx.y;
    const unsigned int* R = br ? r2 : r1;
    const int* BS = br ? b2 : b1;
    int* CNT = br ? c2 : c1;
    int* RP = br ? rp2 : rp1;
    unsigned short* COL = br ? col2 : col1;
    int b = blockIdx.x;
    int s = BS[b], sz = BS[b + 1] - s;
    __shared__ int h[128], sc[128], cur[128];
    if (threadIdx.x < 128) h[threadIdx.x] = 0;
    __syncthreads();
    for (int i = s + threadIdx.x; i < s + sz; i += 256)
        atomicAdd(&h[(R[i] >> 16) & 127], 1);
    __syncthreads();
    if (threadIdx.x < 128) sc[threadIdx.x] = h[threadIdx.x];
    __syncthreads();
    for (int off = 1; off < 128; off <<= 1) {
        int t = 0;
        if (threadIdx.x < 128 && threadIdx.x >= off) t = sc[threadIdx.x - off];
        __syncthreads();
        if (threadIdx.x < 128) sc[threadIdx.x] += t;
        __syncthreads();
    }
    if (threadIdx.x < 128) {
        int excl = sc[threadIdx.x] - h[threadIdx.x];
        cur[threadIdx.x] = excl;
        int node = b * 128 + threadIdx.x;
        if (node < N) { CNT[node] = h[threadIdx.x]; RP[node] = s + excl; }
    }
    __syncthreads();
    for (int i = s + threadIdx.x; i < s + sz; i += 256) {
        unsigned int r = R[i];
        int low = (r >> 16) & 127;
        int p = atomicAdd(&cur[low], 1);          // LDS atomic
        COL[s + p] = (unsigned short)(r & 0xFFFFu);
    }
}

// ------------------------------------------------------------- conversions

__global__ void k_dinv2(const int* __restrict__ c1, const int* __restrict__ c2,
                        float* __restrict__ v1, float* __restrict__ v2, int n) {
    int i = blockIdx.x * blockDim.x + threadIdx.x;
    if (i < n) v1[i] = rsqrtf((float)(c1[i] + 1));
    else if (i < 2 * n) v2[i - n] = rsqrtf((float)(c2[i - n] + 1));
}

__global__ void k_f2b2(const float* __restrict__ x1, const float* __restrict__ x2,
                       unsigned short* __restrict__ o1, unsigned short* __restrict__ o2,
                       int n4) {
    int i = blockIdx.x * blockDim.x + threadIdx.x;
    int stride = gridDim.x * blockDim.x;
    int tot = 2 * n4;
    for (; i < tot; i += stride) {
        int br = i >= n4;
        int e = br ? i - n4 : i;
        float4 v = ((const float4*)(br ? x2 : x1))[e];
        ushort4 o;
        o.x = f2bf(v.x); o.y = f2bf(v.y); o.z = f2bf(v.z); o.w = f2bf(v.w);
        ((ushort4*)(br ? o2 : o1))[e] = o;
    }
}

struct WDesc { const float* in; unsigned short* out; int K; int N; int Npad; };
struct WPack { WDesc d[10]; };

__global__ void k_wconv(WPack p) {
    WDesc w = p.d[blockIdx.y];
    int total = w.K * w.Npad;
    int idx = blockIdx.x * 256 + threadIdx.x;
    if (idx >= total) return;
    int n = idx / w.K, k = idx - n * w.K;
    w.out[idx] = (n < w.N) ? f2bf(w.in[(size_t)k * w.N + n]) : (unsigned short)0;
}

// ------- aggregation: wave/node, lane-halves = even/odd streams, 16-deep
//         fp8 row gathers; weight = dinv[col]*dinv[wid] (dinv L2-resident).

__global__ void k_agg(const unsigned char* __restrict__ g, const int* __restrict__ rowptr,
                      const unsigned short* __restrict__ col,
                      const float* __restrict__ dinv,
                      const float* __restrict__ bias, unsigned short* __restrict__ out,
                      int n, int do_relu) {
    int gtid = blockIdx.x * blockDim.x + threadIdx.x;
    int wid = gtid >> 6;
    if (wid >= n) return;
    int lane = threadIdx.x & 63;
    int half = lane >> 5;   // even/odd neighbor stream
    int fl = lane & 31;     // 8B slice of the 256B fp8 row

    float di = dinv[wid];

    float a[8];
#pragma unroll
    for (int k = 0; k < 8; k++) a[k] = 0.f;

    int r0 = rowptr[wid], r1 = rowptr[wid + 1];
    int base = r0;

    for (; base + 32 <= r1; base += 32) {
        int c[16]; float w[16]; uint2 v[16];
#pragma unroll
        for (int t = 0; t < 16; t++) c[t] = col[base + 2 * t + half];
#pragma unroll
        for (int t = 0; t < 16; t++) w[t] = dinv[c[t]];
#pragma unroll
        for (int t = 0; t < 16; t++)
            v[t] = ((const uint2*)(g + (size_t)c[t] * HDIM))[fl];
#pragma unroll
        for (int t = 0; t < 16; t++) {
            float wt = w[t] * di;
            f32x2 p0 = __builtin_amdgcn_cvt_pk_f32_fp8((int)v[t].x, false);
            f32x2 p1 = __builtin_amdgcn_cvt_pk_f32_fp8((int)v[t].x, true);
            f32x2 p2 = __builtin_amdgcn_cvt_pk_f32_fp8((int)v[t].y, false);
            f32x2 p3 = __builtin_amdgcn_cvt_pk_f32_fp8((int)v[t].y, true);
            a[0] = fmaf(p0[0], wt, a[0]); a[1] = fmaf(p0[1], wt, a[1]);
            a[2] = fmaf(p1[0], wt, a[2]); a[3] = fmaf(p1[1], wt, a[3]);
            a[4] = fmaf(p2[0], wt, a[4]); a[5] = fmaf(p2[1], wt, a[5]);
            a[6] = fmaf(p3[0], wt, a[6]); a[7] = fmaf(p3[1], wt, a[7]);
        }
    }
    for (; base + 16 <= r1; base += 16) {
        int c[8]; float w[8]; uint2 v[8];
#pragma unroll
        for (int t = 0; t < 8; t++) c[t] = col[base + 2 * t + half];
#pragma unroll
        for (int t = 0; t < 8; t++) w[t] = dinv[c[t]];
#pragma unroll
        for (int t = 0; t < 8; t++)
            v[t] = ((const uint2*)(g + (size_t)c[t] * HDIM))[fl];
#pragma unroll
        for (int t = 0; t < 8; t++) {
            float wt = w[t] * di;
            f32x2 p0 = __builtin_amdgcn_cvt_pk_f32_fp8((int)v[t].x, false);
            f32x2 p1 = __builtin_amdgcn_cvt_pk_f32_fp8((int)v[t].x, true);
            f32x2 p2 = __builtin_amdgcn_cvt_pk_f32_fp8((int)v[t].y, false);
            f32x2 p3 = __builtin_amdgcn_cvt_pk_f32_fp8((int)v[t].y, true);
            a[0] = fmaf(p0[0], wt, a[0]); a[1] = fmaf(p0[1], wt, a[1]);
            a[2] = fmaf(p1[0], wt, a[2]); a[3] = fmaf(p1[1], wt, a[3]);
            a[4] = fmaf(p2[0], wt, a[4]); a[5] = fmaf(p2[1], wt, a[5]);
            a[6] = fmaf(p3[0], wt, a[6]); a[7] = fmaf(p3[1], wt, a[7]);
        }
    }
    if (base < r1) {  // remainder 1..15, zero-weight padding
        int c[8]; float w[8]; uint2 v[8];
#pragma unroll
        for (int t = 0; t < 8; t++) {
            int idx = base + 2 * t + half;
            int ok = idx < r1;
            c[t] = col[ok ? idx : r0];
            w[t] = ok ? dinv[c[t]] : 0.f;
        }
#pragma unroll
        for (int t = 0; t < 8; t++)
            v[t] = ((const uint2*)(g + (size_t)c[t] * HDIM))[fl];
#pragma unroll
        for (int t = 0; t < 8; t++) {
            float wt = w[t] * di;
            f32x2 p0 = __builtin_amdgcn_cvt_pk_f32_fp8((int)v[t].x, false);
            f32x2 p1 = __builtin_amdgcn_cvt_pk_f32_fp8((int)v[t].x, true);
            f32x2 p2 = __builtin_amdgcn_cvt_pk_f32_fp8((int)v[t].y, false);
            f32x2 p3 = __builtin_amdgcn_cvt_pk_f32_fp8((int)v[t].y, true);
            a[0] = fmaf(p0[0], wt, a[0]); a[1] = fmaf(p0[1], wt, a[1]);
            a[2] = fmaf(p1[0], wt, a[2]); a[3] = fmaf(p1[1], wt, a[3]);
            a[4] = fmaf(p2[0], wt, a[4]); a[5] = fmaf(p2[1], wt, a[5]);
            a[6] = fmaf(p3[0], wt, a[6]); a[7] = fmaf(p3[1], wt, a[7]);
        }
    }

    // combine even/odd partial sums
#pragma unroll
    for (int k = 0; k < 8; k++) a[k] += __shfl_xor(a[k], 32);

    // self-loop + bias + activation
    float w0 = di * di;
    uint2 sv = ((const uint2*)(g + (size_t)wid * HDIM))[fl];
    f32x2 s0 = __builtin_amdgcn_cvt_pk_f32_fp8((int)sv.x, false);
    f32x2 s1 = __builtin_amdgcn_cvt_pk_f32_fp8((int)sv.x, true);
    f32x2 s2 = __builtin_amdgcn_cvt_pk_f32_fp8((int)sv.y, false);
    f32x2 s3 = __builtin_amdgcn_cvt_pk_f32_fp8((int)sv.y, true);
    float sf[8] = {s0[0], s0[1], s1[0], s1[1], s2[0], s2[1], s3[0], s3[1]};
    u16x8 o;
#pragma unroll
    for (int k = 0; k < 8; k++) {
        float x = fmaf(sf[k], w0, a[k]) + bias[fl * 8 + k];
        if (do_relu) x = fmaxf(x, 0.f);
        o[k] = f2bf(x);
    }
    if (half == 0)
        ((u16x8*)(out + (size_t)wid * HDIM))[fl] = o;
}

// --------------------------------------------------- bf16 MFMA GEMM 128x128
// EPI 0: raw -> fp8 C.  EPI 1: bias+relu -> bf16.  EPI 2: bias+sigmoid -> fp32.

template <int EPI>
__global__ __launch_bounds__(256) void k_gemm(const unsigned short* __restrict__ A,
                                              const unsigned short* __restrict__ Bt,
                                              const float* __restrict__ bias,
                                              void* __restrict__ Cout,
                                              int M, int K, int Nc) {
    __shared__ __align__(16) unsigned short As[128 * 32];
    __shared__ __align__(16) unsigned short Bs[128 * 32];
    int tid = threadIdx.x;
    int wid = tid >> 6, lane = tid & 63;
    int wr = wid >> 1, wc = wid & 1;
    int mb = blockIdx.y * 128, nb = blockIdx.x * 128;

    int sr = tid >> 2;
    int ssl = (tid & 3) ^ ((sr >> 1) & 3);
    int ar0 = mb + sr;      if (ar0 > M - 1) ar0 = M - 1;
    int ar1 = mb + sr + 64; if (ar1 > M - 1) ar1 = M - 1;
    const unsigned short* gA0 = A + (size_t)ar0 * K + ssl * 8;
    const unsigned short* gA1 = A + (size_t)ar1 * K + ssl * 8;
    const unsigned short* gB0 = Bt + (size_t)(nb + sr) * K + ssl * 8;
    const unsigned short* gB1 = Bt + (size_t)(nb + sr + 64) * K + ssl * 8;
    unsigned short* ldsA = As + tid * 8;
    unsigned short* ldsB = Bs + tid * 8;

    f32x4 acc[4][4];
#pragma unroll
    for (int m = 0; m < 4; m++)
#pragma unroll
        for (int n = 0; n < 4; n++) acc[m][n] = (f32x4){0.f, 0.f, 0.f, 0.f};

    int l15 = lane & 15, ks = lane >> 4;

    for (int k0 = 0; k0 < K; k0 += 32) {
        gload16(gA0 + k0, ldsA);
        gload16(gA1 + k0, ldsA + 2048);
        gload16(gB0 + k0, ldsB);
        gload16(gB1 + k0, ldsB + 2048);
        __syncthreads();

        short8 af[4], bfr[4];
#pragma unroll
        for (int m = 0; m < 4; m++) {
            int row = wr * 64 + m * 16 + l15;
            int slot = ks ^ ((row >> 1) & 3);
            af[m] = *(const short8*)((const char*)As + row * 64 + slot * 16);
        }
#pragma unroll
        for (int n = 0; n < 4; n++) {
            int row = wc * 64 + n * 16 + l15;
            int slot = ks ^ ((row >> 1) & 3);
            bfr[n] = *(const short8*)((const char*)Bs + row * 64 + slot * 16);
        }
#pragma unroll
        for (int m = 0; m < 4; m++)
#pragma unroll
            for (int n = 0; n < 4; n++)
                acc[m][n] = __builtin_amdgcn_mfma_f32_16x16x32_bf16(af[m], bfr[n], acc[m][n], 0, 0, 0);
        __syncthreads();
    }

    int lq = lane >> 4;
#pragma unroll
    for (int m = 0; m < 4; m++) {
#pragma unroll
        for (int n = 0; n < 4; n++) {
            int gcol = nb + wc * 64 + n * 16 + l15;
#pragma unroll
            for (int r = 0; r < 4; r++) {
                int grow = mb + wr * 64 + m * 16 + lq * 4 + r;
                if (grow >= M) continue;
                float v = acc[m][n][r];
                if (EPI == 0) {
                    ((unsigned char*)Cout)[(size_t)grow * Nc + gcol] = f2fp8(v);
                } else if (EPI == 1) {
                    v += bias[gcol];
                    v = fmaxf(v, 0.f);
                    ((unsigned short*)Cout)[(size_t)grow * Nc + gcol] = f2bf(v);
                } else {
                    if (gcol < Nc) {
                        v += bias[gcol];
                        v = 1.f / (1.f + expf(-v));
                        ((float*)Cout)[(size_t)grow * Nc + gcol] = v;
                    }
                }
            }
        }
    }
}

// ------------------------------------------------------------- gate fusion

__global__ void k_gate(const unsigned short* __restrict__ h1, const unsigned short* __restrict__ h2,
                       const float* __restrict__ w1, const float* __restrict__ w1b,
                       const float* __restrict__ w2, const float* __restrict__ w2b,
                       unsigned short* __restrict__ m, int n) {
    int gtid = blockIdx.x * blockDim.x + threadIdx.x;
    int wid = gtid >> 6;
    int lane = threadIdx.x & 63;
    if (wid >= n) return;
    ushort4 av = ((const ushort4*)(h1 + (size_t)wid * HDIM))[lane];
    ushort4 bv = ((const ushort4*)(h2 + (size_t)wid * HDIM))[lane];
    float4 wa = ((const float4*)w1)[lane];
    float4 wb = ((const float4*)w2)[lane];
    float a0 = bf2f(av.x), a1 = bf2f(av.y), a2 = bf2f(av.z), a3 = bf2f(av.w);
    float b0 = bf2f(bv.x), b1 = bf2f(bv.y), b2 = bf2f(bv.z), b3 = bf2f(bv.w);
    float d1 = a0 * wa.x + a1 * wa.y + a2 * wa.z + a3 * wa.w;
    float d2 = b0 * wb.x + b1 * wb.y + b2 * wb.z + b3 * wb.w;
    for (int off = 32; off > 0; off >>= 1) {
        d1 += __shfl_xor(d1, off);
        d2 += __shfl_xor(d2, off);
    }
    float f1 = 1.f / (1.f + expf(-(d1 + w1b[0])));
    float f2 = 1.f / (1.f + expf(-(d2 + w2b[0])));
    float f = f1 / (f1 + f2);
    ushort4 o;
    o.x = f2bf(f * a0 + (1.f - f) * b0);
    o.y = f2bf(f * a1 + (1.f - f) * b1);
    o.z = f2bf(f * a2 + (1.f - f) * b2);
    o.w = f2bf(f * a3 + (1.f - f) * b3);
    ((ushort4*)(m + (size_t)wid * HDIM))[lane] = o;
}

// ------------------------------------------------------------------ launch

extern "C" void kernel_launch(void* const* d_in, const int* in_sizes, int n_in,
                              void* d_out, int out_size, void* d_ws, size_t ws_size,
                              hipStream_t stream) {
    (void)n_in; (void)out_size; (void)ws_size;
    const int N = N_NODES, E = E_EDGES;

    const float* x1; const float* x2; const int* ei1; const int* ei2;
    if (in_sizes[1] == 2 * E) {
        x1 = (const float*)d_in[0]; ei1 = (const int*)d_in[1];
        x2 = (const float*)d_in[2]; ei2 = (const int*)d_in[3];
    } else {
        x1 = (const float*)d_in[0]; x2 = (const float*)d_in[1];
        ei1 = (const int*)d_in[2]; ei2 = (const int*)d_in[3];
    }
    const float* W[2][4]; const float* Bv[2][4];
    int idx = 4;
    for (int br = 0; br < 2; br++)
        for (int l = 0; l < 4; l++) {
            W[br][l] = (const float*)d_in[idx++];
            Bv[br][l] = (const float*)d_in[idx++];
        }
    const float* w1W  = (const float*)d_in[20];
    const float* w1b  = (const float*)d_in[21];
    const float* w2W  = (const float*)d_in[22];
    const float* w2b  = (const float*)d_in[23];
    const float* finW = (const float*)d_in[24];
    const float* finb = (const float*)d_in[25];
    const float* outW = (const float*)d_in[26];
    const float* outb = (const float*)d_in[27];
    float* out = (float*)d_out;

    size_t off = 0;
    auto alloc = [&](size_t bytes) {
        void* p = (char*)d_ws + off;
        off = (off + bytes + 255) & ~(size_t)255;
        return p;
    };
    unsigned short* x1b = (unsigned short*)alloc((size_t)N * F_IN * 2);  // also fin-out t
    unsigned short* x2b = (unsigned short*)alloc((size_t)N * F_IN * 2);
    unsigned char*  g8  = (unsigned char*)alloc((size_t)N * HDIM);       // fp8 GEMM out
    unsigned short* mb_ = (unsigned short*)alloc((size_t)N * HDIM * 2);
    unsigned short* h1b = (unsigned short*)alloc((size_t)N * HDIM * 2);
    unsigned short* h2b = (unsigned short*)alloc((size_t)N * HDIM * 2);
    unsigned short* Wt[2][4];
    Wt[0][0] = (unsigned short*)alloc((size_t)HDIM * F_IN * 2);
    for (int l = 1; l < 4; l++) Wt[0][l] = (unsigned short*)alloc((size_t)HDIM * HDIM * 2);
    Wt[1][0] = (unsigned short*)alloc((size_t)HDIM * F_IN * 2);
    for (int l = 1; l < 4; l++) Wt[1][l] = (unsigned short*)alloc((size_t)HDIM * HDIM * 2);
    unsigned short* finWt = (unsigned short*)alloc((size_t)HDIM * HDIM * 2);
    unsigned short* outWt = (unsigned short*)alloc((size_t)128 * HDIM * 2);
    unsigned short* col1 = (unsigned short*)alloc((size_t)E * 2);
    unsigned short* col2 = (unsigned short*)alloc((size_t)E * 2);
    unsigned int* rec1 = (unsigned int*)alloc((size_t)E * 4);
    unsigned int* rec2 = (unsigned int*)alloc((size_t)E * 4);
    int* hist1  = (int*)alloc((size_t)NB1 * NBLK * 4);
    int* hist2  = (int*)alloc((size_t)NB1 * NBLK * 4);
    int* tot1   = (int*)alloc((size_t)NB1 * 4);
    int* tot2   = (int*)alloc((size_t)NB1 * 4);
    int* bs1    = (int*)alloc((size_t)(NB1 + 1) * 4);
    int* bs2    = (int*)alloc((size_t)(NB1 + 1) * 4);
    int* rp1    = (int*)alloc((size_t)(N + 1) * 4);
    int* rp2    = (int*)alloc((size_t)(N + 1) * 4);
    int* cnt1   = (int*)alloc((size_t)N * 4);
    int* cnt2   = (int*)alloc((size_t)N * 4);
    float* di1  = (float*)alloc((size_t)N * 4);
    float* di2  = (float*)alloc((size_t)N * 4);

    const int BLK = 256;
    int nwaves_grid = (N * 64 + BLK - 1) / BLK;   // 12500
    int mtiles = (N + 127) / 128;                 // 391
    dim3 grid_h(HDIM / 128, mtiles);
    dim3 grid_o(1, mtiles);

    // weight conversion + x conversion (independent of CSR build)
    WPack wp;
    wp.d[0] = {W[0][0], Wt[0][0], F_IN, HDIM, HDIM};
    wp.d[1] = {W[0][1], Wt[0][1], HDIM, HDIM, HDIM};
    wp.d[2] = {W[0][2], Wt[0][2], HDIM, HDIM, HDIM};
    wp.d[3] = {W[0][3], Wt[0][3], HDIM, HDIM, HDIM};
    wp.d[4] = {W[1][0], Wt[1][0], F_IN, HDIM, HDIM};
    wp.d[5] = {W[1][1], Wt[1][1], HDIM, HDIM, HDIM};
    wp.d[6] = {W[1][2], Wt[1][2], HDIM, HDIM, HDIM};
    wp.d[7] = {W[1][3], Wt[1][3], HDIM, HDIM, HDIM};
    wp.d[8] = {finW, finWt, HDIM, HDIM, HDIM};
    wp.d[9] = {outW, outWt, HDIM, L_OUT, 128};
    k_wconv<<<dim3(512, 10), BLK, 0, stream>>>(wp);
    k_f2b2<<<4096, BLK, 0, stream>>>(x1, x2, x1b, x2b, N * F_IN / 4);

    // atomic-free CSR build (two-level counting sort), both branches
    k_hist<<<dim3(NBLK, 2), BLK, 0, stream>>>(ei1 + E, ei2 + E, hist1, hist2, E);
    k_scanb<<<dim3(NB1, 2), BLK, 0, stream>>>(hist1, hist2, tot1, tot2);
    k_bstart<<<dim3(1, 2), 512, 0, stream>>>(tot1, tot2, bs1, bs2, rp1, rp2, N, E);
    k_scatter<<<dim3(NBLK, 2), BLK, 0, stream>>>(ei1, ei1 + E, ei2, ei2 + E,
                                                 hist1, hist2, bs1, bs2, rec1, rec2, E);
    k_sort<<<dim3(NB1, 2), BLK, 0, stream>>>(rec1, rec2, bs1, bs2,
                                             cnt1, cnt2, rp1, rp2, col1, col2, N);
    k_dinv2<<<(2 * N + BLK - 1) / BLK, BLK, 0, stream>>>(cnt1, cnt2, di1, di2, N);

    // branch-sequential layers: GEMM -> agg immediately (g8 hot in L2)
    for (int br = 0; br < 2; br++) {
        const unsigned short* col = br ? col2 : col1;
        const int* rp = br ? rp2 : rp1;
        const float* di = br ? di2 : di1;
        const unsigned short* xb = br ? x2b : x1b;
        unsigned short* hb = br ? h2b : h1b;

        k_gemm<0><<<grid_h, BLK, 0, stream>>>(xb, Wt[br][0], nullptr, g8, N, F_IN, HDIM);
        k_agg<<<nwaves_grid, BLK, 0, stream>>>(g8, rp, col, di, Bv[br][0], hb, N, 1);
        for (int l = 1; l <= 2; l++) {
            k_gemm<0><<<grid_h, BLK, 0, stream>>>(hb, Wt[br][l], nullptr, g8, N, HDIM, HDIM);
            k_agg<<<nwaves_grid, BLK, 0, stream>>>(g8, rp, col, di, Bv[br][l], hb, N, 1);
        }
        k_gemm<0><<<grid_h, BLK, 0, stream>>>(hb, Wt[br][3], nullptr, g8, N, HDIM, HDIM);
        k_agg<<<nwaves_grid, BLK, 0, stream>>>(g8, rp, col, di, Bv[br][3], hb, N, 0);
    }

    k_gate<<<nwaves_grid, BLK, 0, stream>>>(h1b, h2b, w1W, w1b, w2W, w2b, mb_, N);
    k_gemm<1><<<grid_h, BLK, 0, stream>>>(mb_, finWt, finb, x1b, N, HDIM, HDIM);
    k_gemm<2><<<grid_o, BLK, 0, stream>>>(x1b, outWt, outb, out, N, HDIM, L_OUT);
}